// Round 1
// baseline (382.954 us; speedup 1.0000x reference)
//
#include <hip/hip_runtime.h>

typedef __attribute__((ext_vector_type(8))) short short8;
typedef __attribute__((ext_vector_type(4))) float f32x4;

#define S_LEN 2048
#define HIDN  1024
#define NHEAD 16
#define DHEAD 64

__device__ __forceinline__ short f2bf(float x) {
    unsigned u = __float_as_uint(x);
    u += 0x7fffu + ((u >> 16) & 1u);
    return (short)(u >> 16);
}

typedef const __attribute__((address_space(1))) void* gas_ptr;
typedef __attribute__((address_space(3))) void* las_ptr;

__device__ __forceinline__ void gload_lds16(const short* g, short* l) {
    __builtin_amdgcn_global_load_lds((gas_ptr)g, (las_ptr)l, 16, 0, 0);
}

// ---------------- fp32 -> bf16 conversion ----------------
__global__ __launch_bounds__(256) void cvt_kernel(const float* __restrict__ in,
                                                  short* __restrict__ out, int n) {
    int i = (blockIdx.x * 256 + threadIdx.x) * 8;
    if (i + 8 > n) return;
    float4 a = *(const float4*)(in + i);
    float4 b = *(const float4*)(in + i + 4);
    short8 o;
    o[0] = f2bf(a.x); o[1] = f2bf(a.y); o[2] = f2bf(a.z); o[3] = f2bf(a.w);
    o[4] = f2bf(b.x); o[5] = f2bf(b.y); o[6] = f2bf(b.z); o[7] = f2bf(b.w);
    *(short8*)(out + i) = o;
}

// ---------------- GEMM: C[M,N] = A[M,K] @ W[N,K]^T + bias ----------------
// M=8192, N=1024, K=1024.  128x128 tile, BK=32, 4 waves (2x2), 16x16x32 MFMA.
// A_FP32: A is fp32 (reg-staged + converted); else bf16 via global_load_lds.
// OMODE 0: out bf16 head-split [B,H,S,D]; 1: out bf16 transposed [B,H,D,S]; 2: out fp32 [M,N].
template<bool A_FP32, int OMODE>
__global__ __launch_bounds__(256) void gemm_bt(const void* __restrict__ Aptr,
                                               const short* __restrict__ Wb,
                                               const float* __restrict__ bias,
                                               void* __restrict__ Out) {
    int mt = blockIdx.x & 63;
    int nt = blockIdx.x >> 6;
    int m0 = mt * 128, n0 = nt * 128;
    int tid = threadIdx.x;
    int w = tid >> 6, l = tid & 63, g = l >> 4, r = l & 15;
    int wm = w >> 1, wn = w & 1;

    __shared__ short As[128 * 32];
    __shared__ short Bs[128 * 32];

    f32x4 acc[4][4];
#pragma unroll
    for (int i = 0; i < 4; i++)
#pragma unroll
        for (int j = 0; j < 4; j++) acc[i][j] = (f32x4){0.f, 0.f, 0.f, 0.f};

    for (int kt = 0; kt < HIDN / 32; ++kt) {
        __syncthreads();
        if constexpr (A_FP32) {
            const float* A = (const float*)Aptr;
            int row = tid >> 1, colh = (tid & 1) * 16;
            const float* gp = A + (size_t)(m0 + row) * HIDN + kt * 32 + colh;
            float4 v0 = ((const float4*)gp)[0];
            float4 v1 = ((const float4*)gp)[1];
            float4 v2 = ((const float4*)gp)[2];
            float4 v3 = ((const float4*)gp)[3];
            short8 p0, p1;
            p0[0] = f2bf(v0.x); p0[1] = f2bf(v0.y); p0[2] = f2bf(v0.z); p0[3] = f2bf(v0.w);
            p0[4] = f2bf(v1.x); p0[5] = f2bf(v1.y); p0[6] = f2bf(v1.z); p0[7] = f2bf(v1.w);
            p1[0] = f2bf(v2.x); p1[1] = f2bf(v2.y); p1[2] = f2bf(v2.z); p1[3] = f2bf(v2.w);
            p1[4] = f2bf(v3.x); p1[5] = f2bf(v3.y); p1[6] = f2bf(v3.z); p1[7] = f2bf(v3.w);
            *(short8*)(As + row * 32 + colh) = p0;
            *(short8*)(As + row * 32 + colh + 8) = p1;
        } else {
            const short* A = (const short*)Aptr;
#pragma unroll
            for (int i = 0; i < 2; i++) {
                int c = w + i * 4;                 // wave-uniform chunk id
                int o = c * 1024 + l * 16;         // byte offset in 8KB tile
                int row = o >> 6, colB = o & 63;
                gload_lds16(A + (size_t)(m0 + row) * HIDN + kt * 32 + (colB >> 1),
                            As + c * 512);
            }
        }
#pragma unroll
        for (int i = 0; i < 2; i++) {
            int c = w + i * 4;
            int o = c * 1024 + l * 16;
            int row = o >> 6, colB = o & 63;
            gload_lds16(Wb + (size_t)(n0 + row) * HIDN + kt * 32 + (colB >> 1),
                        Bs + c * 512);
        }
        __syncthreads();

        short8 af[4], bfr[4];
#pragma unroll
        for (int i = 0; i < 4; i++)
            af[i] = *(const short8*)(As + (wm * 64 + i * 16 + r) * 32 + g * 8);
#pragma unroll
        for (int j = 0; j < 4; j++)
            bfr[j] = *(const short8*)(Bs + (wn * 64 + j * 16 + r) * 32 + g * 8);
#pragma unroll
        for (int i = 0; i < 4; i++)
#pragma unroll
            for (int j = 0; j < 4; j++)
                acc[i][j] = __builtin_amdgcn_mfma_f32_16x16x32_bf16(af[i], bfr[j], acc[i][j], 0, 0, 0);
    }

#pragma unroll
    for (int j = 0; j < 4; j++) {
        int n_g = n0 + wn * 64 + j * 16 + r;
        float bv = bias[n_g];
#pragma unroll
        for (int i = 0; i < 4; i++) {
#pragma unroll
            for (int rr = 0; rr < 4; rr++) {
                int m_g = m0 + wm * 64 + i * 16 + g * 4 + rr;
                float val = acc[i][j][rr] + bv;
                if constexpr (OMODE == 0) {
                    int b = m_g >> 11, s = m_g & 2047, h = n_g >> 6, d = n_g & 63;
                    ((short*)Out)[(((size_t)(b * NHEAD + h)) * S_LEN + s) * DHEAD + d] = f2bf(val);
                } else if constexpr (OMODE == 1) {
                    int b = m_g >> 11, s = m_g & 2047, h = n_g >> 6, d = n_g & 63;
                    ((short*)Out)[(((size_t)(b * NHEAD + h)) * DHEAD + d) * S_LEN + s] = f2bf(val);
                } else {
                    ((float*)Out)[(size_t)m_g * HIDN + n_g] = val;
                }
            }
        }
    }
}

// ---------------- flash attention (causal) ----------------
// grid = 64 (b,h) * 32 q-tiles. block = 256 (4 waves). Q-tile = 64 rows (16/wave).
// Qh,Kh: [B,H,S,D] bf16.  VhT: [B,H,D,S] bf16.  ctx out: [B,S,H*D] bf16.
__global__ __launch_bounds__(256) void attn_kernel(const short* __restrict__ Qh,
                                                   const short* __restrict__ Kh,
                                                   const short* __restrict__ VhT,
                                                   short* __restrict__ ctx) {
    int bid = blockIdx.x;
    int bh = bid >> 5;
    int qt = 31 - (bid & 31);  // heavy tiles dispatch first
    int tid = threadIdx.x;
    int w = tid >> 6, l = tid & 63, g = l >> 4, r = l & 15;

    __shared__ short Ks[64 * 72];       // [k][d] padded
    __shared__ short Vs[64 * 72];       // [d][k] padded (V^T tile)
    __shared__ short Ps[4][16 * 72];    // per-wave P tile [q][k] padded

    const short* Qb = Qh + (size_t)bh * S_LEN * DHEAD;
    const short* Kb = Kh + (size_t)bh * S_LEN * DHEAD;
    const short* Vb = VhT + (size_t)bh * DHEAD * S_LEN;

    short8 qf[2];
    {
        const short* qp = Qb + (size_t)(qt * 64 + w * 16 + r) * DHEAD + g * 8;
        qf[0] = *(const short8*)qp;
        qf[1] = *(const short8*)(qp + 32);
    }

    f32x4 acc[4];
#pragma unroll
    for (int nd = 0; nd < 4; nd++) acc[nd] = (f32x4){0.f, 0.f, 0.f, 0.f};
    float mrun[4], lrun[4];
#pragma unroll
    for (int rr = 0; rr < 4; rr++) { mrun[rr] = -1e30f; lrun[rr] = 0.f; }

    for (int kt = 0; kt <= qt; ++kt) {
        __syncthreads();
        // stage K tile [64][64] -> Ks padded
#pragma unroll
        for (int i = 0; i < 2; i++) {
            int o = i * 4096 + tid * 16;     // byte in 8KB tile
            int krow = o >> 7, colB = o & 127;
            short8 v = *(const short8*)(Kb + (size_t)(kt * 64 + krow) * DHEAD + (colB >> 1));
            *(short8*)(Ks + krow * 72 + (colB >> 1)) = v;
        }
        // stage V^T tile [64 d][64 k] -> Vs padded
#pragma unroll
        for (int i = 0; i < 2; i++) {
            int o = i * 4096 + tid * 16;
            int drow = o >> 7, colB = o & 127;
            short8 v = *(const short8*)(Vb + (size_t)drow * S_LEN + kt * 64 + (colB >> 1));
            *(short8*)(Vs + drow * 72 + (colB >> 1)) = v;
        }
        __syncthreads();

        // S = Q K^T  (wave: 16 q-rows x 64 k-cols)
        f32x4 sf[4];
#pragma unroll
        for (int nk = 0; nk < 4; nk++) {
            short8 b0 = *(const short8*)(Ks + (nk * 16 + r) * 72 + g * 8);
            short8 b1 = *(const short8*)(Ks + (nk * 16 + r) * 72 + 32 + g * 8);
            f32x4 t = (f32x4){0.f, 0.f, 0.f, 0.f};
            t = __builtin_amdgcn_mfma_f32_16x16x32_bf16(qf[0], b0, t, 0, 0, 0);
            t = __builtin_amdgcn_mfma_f32_16x16x32_bf16(qf[1], b1, t, 0, 0, 0);
            sf[nk] = t;
        }
        bool diag = (kt == qt);
#pragma unroll
        for (int nk = 0; nk < 4; nk++)
#pragma unroll
            for (int rr = 0; rr < 4; rr++) {
                float sv = sf[nk][rr] * 0.125f;  // 1/sqrt(64)
                if (diag && (nk * 16 + r) > (w * 16 + g * 4 + rr)) sv = -1e30f;
                sf[nk][rr] = sv;
            }
        // online softmax; row of lane = g*4+rr (16 lanes per row-group share state)
        float fac[4];
#pragma unroll
        for (int rr = 0; rr < 4; rr++) {
            float tm = fmaxf(fmaxf(sf[0][rr], sf[1][rr]), fmaxf(sf[2][rr], sf[3][rr]));
#pragma unroll
            for (int m = 1; m < 16; m <<= 1) tm = fmaxf(tm, __shfl_xor(tm, m));
            float mn = fmaxf(mrun[rr], tm);
            float f = __expf(mrun[rr] - mn);
            float rs = 0.f;
#pragma unroll
            for (int nk = 0; nk < 4; nk++) {
                float p = __expf(sf[nk][rr] - mn);
                sf[nk][rr] = p;
                rs += p;
            }
#pragma unroll
            for (int m = 1; m < 16; m <<= 1) rs += __shfl_xor(rs, m);
            lrun[rr] = lrun[rr] * f + rs;
            mrun[rr] = mn;
            fac[rr] = f;
        }
#pragma unroll
        for (int nd = 0; nd < 4; nd++)
#pragma unroll
            for (int rr = 0; rr < 4; rr++) acc[nd][rr] *= fac[rr];
        // P -> LDS (per-wave buffer, in-wave dependency)
#pragma unroll
        for (int nk = 0; nk < 4; nk++)
#pragma unroll
            for (int rr = 0; rr < 4; rr++)
                Ps[w][(g * 4 + rr) * 72 + nk * 16 + r] = f2bf(sf[nk][rr]);
        // ctx += P V
        short8 pa0 = *(const short8*)(&Ps[w][r * 72 + g * 8]);
        short8 pa1 = *(const short8*)(&Ps[w][r * 72 + 32 + g * 8]);
#pragma unroll
        for (int nd = 0; nd < 4; nd++) {
            short8 vb0 = *(const short8*)(Vs + (nd * 16 + r) * 72 + g * 8);
            short8 vb1 = *(const short8*)(Vs + (nd * 16 + r) * 72 + 32 + g * 8);
            acc[nd] = __builtin_amdgcn_mfma_f32_16x16x32_bf16(pa0, vb0, acc[nd], 0, 0, 0);
            acc[nd] = __builtin_amdgcn_mfma_f32_16x16x32_bf16(pa1, vb1, acc[nd], 0, 0, 0);
        }
    }

    int b = bh >> 4, h = bh & 15;
#pragma unroll
    for (int rr = 0; rr < 4; rr++) {
        int q_g = qt * 64 + w * 16 + g * 4 + rr;
        float inv = 1.0f / lrun[rr];
#pragma unroll
        for (int nd = 0; nd < 4; nd++)
            ctx[((size_t)(b * S_LEN + q_g)) * HIDN + h * DHEAD + nd * 16 + r] =
                f2bf(acc[nd][rr] * inv);
    }
}

extern "C" void kernel_launch(void* const* d_in, const int* in_sizes, int n_in,
                              void* d_out, int out_size, void* d_ws, size_t ws_size,
                              hipStream_t stream) {
    const float* q  = (const float*)d_in[0];
    const float* k  = (const float*)d_in[1];
    const float* v  = (const float*)d_in[2];
    // d_in[3] = attn_mask: structurally causal, not read.
    const float* Wq = (const float*)d_in[4];
    const float* bq = (const float*)d_in[5];
    const float* Wk = (const float*)d_in[6];
    const float* bk = (const float*)d_in[7];
    const float* Wv = (const float*)d_in[8];
    const float* bv = (const float*)d_in[9];
    const float* Wo = (const float*)d_in[10];
    const float* bo = (const float*)d_in[11];

    char* ws = (char*)d_ws;
    const size_t ACT = (size_t)8192 * 1024 * 2;   // 16 MB per bf16 activation
    const size_t WSZ = (size_t)1024 * 1024 * 2;   // 2 MB per bf16 weight
    short* Qh  = (short*)(ws);
    short* Kh  = (short*)(ws + ACT);
    short* VhT = (short*)(ws + 2 * ACT);
    short* ctx = (short*)(ws + 3 * ACT);
    short* Wqb = (short*)(ws + 4 * ACT);
    short* Wkb = (short*)(ws + 4 * ACT + WSZ);
    short* Wvb = (short*)(ws + 4 * ACT + 2 * WSZ);
    short* Wob = (short*)(ws + 4 * ACT + 3 * WSZ);

    const int NW = 1024 * 1024;
    cvt_kernel<<<512, 256, 0, stream>>>(Wq, Wqb, NW);
    cvt_kernel<<<512, 256, 0, stream>>>(Wk, Wkb, NW);
    cvt_kernel<<<512, 256, 0, stream>>>(Wv, Wvb, NW);
    cvt_kernel<<<512, 256, 0, stream>>>(Wo, Wob, NW);

    gemm_bt<true, 0><<<512, 256, 0, stream>>>(q, Wqb, bq, Qh);
    gemm_bt<true, 0><<<512, 256, 0, stream>>>(k, Wkb, bk, Kh);
    gemm_bt<true, 1><<<512, 256, 0, stream>>>(v, Wvb, bv, VhT);

    attn_kernel<<<2048, 256, 0, stream>>>(Qh, Kh, VhT, ctx);

    gemm_bt<false, 2><<<512, 256, 0, stream>>>(ctx, Wob, bo, d_out);
}

// Round 3
// 311.279 us; speedup vs baseline: 1.2303x; 1.2303x over previous
//
#include <hip/hip_runtime.h>

typedef __attribute__((ext_vector_type(8))) short short8;
typedef __attribute__((ext_vector_type(4))) float f32x4;
typedef __attribute__((ext_vector_type(16))) float f32x16;

#define S_LEN 2048
#define HIDN  1024
#define NHEAD 16
#define DHEAD 64

__device__ __forceinline__ short f2bf(float x) {
    unsigned u = __float_as_uint(x);
    u += 0x7fffu + ((u >> 16) & 1u);
    return (short)(u >> 16);
}

typedef const __attribute__((address_space(1))) void* gas_ptr;
typedef __attribute__((address_space(3))) void* las_ptr;

__device__ __forceinline__ void gload_lds16(const short* g, short* l) {
    __builtin_amdgcn_global_load_lds((gas_ptr)g, (las_ptr)l, 16, 0, 0);
}

__device__ __forceinline__ unsigned cvtpk(float lo, float hi_) {
    unsigned r;
    asm("v_cvt_pk_bf16_f32 %0, %1, %2" : "=v"(r) : "v"(lo), "v"(hi_));
    return r;
}

// v_permlane32_swap_b32 vdst, vsrc: vdst[32:63] <-> vsrc[0:31].
// "+&v" early-clobber: forbid the allocator from tying the two operands.
__device__ __forceinline__ void plswap(unsigned& x, unsigned& y) {
    asm("v_permlane32_swap_b32 %0, %1" : "+&v"(x), "+&v"(y));
}

__device__ __forceinline__ short8 mk8(unsigned a, unsigned b, unsigned c, unsigned d) {
    union { unsigned u[4]; short8 s; } t;
    t.u[0] = a; t.u[1] = b; t.u[2] = c; t.u[3] = d;
    return t.s;
}

// ---------------- fp32 -> bf16 conversion ----------------
__global__ __launch_bounds__(256) void cvt_kernel(const float* __restrict__ in,
                                                  short* __restrict__ out, int n) {
    int i = (blockIdx.x * 256 + threadIdx.x) * 8;
    if (i + 8 > n) return;
    float4 a = *(const float4*)(in + i);
    float4 b = *(const float4*)(in + i + 4);
    short8 o;
    o[0] = f2bf(a.x); o[1] = f2bf(a.y); o[2] = f2bf(a.z); o[3] = f2bf(a.w);
    o[4] = f2bf(b.x); o[5] = f2bf(b.y); o[6] = f2bf(b.z); o[7] = f2bf(b.w);
    *(short8*)(out + i) = o;
}

// ---------------- GEMM: C[M,N] = (A[M,K] @ W[N,K]^T + bias) * oscale ----------------
template<bool A_FP32, int OMODE>
__global__ __launch_bounds__(256) void gemm_bt(const void* __restrict__ Aptr,
                                               const short* __restrict__ Wb,
                                               const float* __restrict__ bias,
                                               void* __restrict__ Out, float oscale) {
    int mt = blockIdx.x & 63;
    int nt = blockIdx.x >> 6;
    int m0 = mt * 128, n0 = nt * 128;
    int tid = threadIdx.x;
    int w = tid >> 6, l = tid & 63, g = l >> 4, r = l & 15;
    int wm = w >> 1, wn = w & 1;

    __shared__ short As[128 * 32];
    __shared__ short Bs[128 * 32];

    f32x4 acc[4][4];
#pragma unroll
    for (int i = 0; i < 4; i++)
#pragma unroll
        for (int j = 0; j < 4; j++) acc[i][j] = (f32x4){0.f, 0.f, 0.f, 0.f};

    for (int kt = 0; kt < HIDN / 32; ++kt) {
        __syncthreads();
        if constexpr (A_FP32) {
            const float* A = (const float*)Aptr;
            int row = tid >> 1, colh = (tid & 1) * 16;
            const float* gp = A + (size_t)(m0 + row) * HIDN + kt * 32 + colh;
            float4 v0 = ((const float4*)gp)[0];
            float4 v1 = ((const float4*)gp)[1];
            float4 v2 = ((const float4*)gp)[2];
            float4 v3 = ((const float4*)gp)[3];
            short8 p0, p1;
            p0[0] = f2bf(v0.x); p0[1] = f2bf(v0.y); p0[2] = f2bf(v0.z); p0[3] = f2bf(v0.w);
            p0[4] = f2bf(v1.x); p0[5] = f2bf(v1.y); p0[6] = f2bf(v1.z); p0[7] = f2bf(v1.w);
            p1[0] = f2bf(v2.x); p1[1] = f2bf(v2.y); p1[2] = f2bf(v2.z); p1[3] = f2bf(v2.w);
            p1[4] = f2bf(v3.x); p1[5] = f2bf(v3.y); p1[6] = f2bf(v3.z); p1[7] = f2bf(v3.w);
            *(short8*)(As + row * 32 + colh) = p0;
            *(short8*)(As + row * 32 + colh + 8) = p1;
        } else {
            const short* A = (const short*)Aptr;
#pragma unroll
            for (int i = 0; i < 2; i++) {
                int c = w + i * 4;
                int o = c * 1024 + l * 16;
                int row = o >> 6, colB = o & 63;
                gload_lds16(A + (size_t)(m0 + row) * HIDN + kt * 32 + (colB >> 1),
                            As + c * 512);
            }
        }
#pragma unroll
        for (int i = 0; i < 2; i++) {
            int c = w + i * 4;
            int o = c * 1024 + l * 16;
            int row = o >> 6, colB = o & 63;
            gload_lds16(Wb + (size_t)(n0 + row) * HIDN + kt * 32 + (colB >> 1),
                        Bs + c * 512);
        }
        __syncthreads();

        short8 af[4], bfr[4];
#pragma unroll
        for (int i = 0; i < 4; i++)
            af[i] = *(const short8*)(As + (wm * 64 + i * 16 + r) * 32 + g * 8);
#pragma unroll
        for (int j = 0; j < 4; j++)
            bfr[j] = *(const short8*)(Bs + (wn * 64 + j * 16 + r) * 32 + g * 8);
#pragma unroll
        for (int i = 0; i < 4; i++)
#pragma unroll
            for (int j = 0; j < 4; j++)
                acc[i][j] = __builtin_amdgcn_mfma_f32_16x16x32_bf16(af[i], bfr[j], acc[i][j], 0, 0, 0);
    }

#pragma unroll
    for (int j = 0; j < 4; j++) {
        int n_g = n0 + wn * 64 + j * 16 + r;
        float bv = bias[n_g];
#pragma unroll
        for (int i = 0; i < 4; i++) {
#pragma unroll
            for (int rr = 0; rr < 4; rr++) {
                int m_g = m0 + wm * 64 + i * 16 + g * 4 + rr;
                float val = (acc[i][j][rr] + bv) * oscale;
                if constexpr (OMODE == 0) {
                    int b = m_g >> 11, s = m_g & 2047, h = n_g >> 6, d = n_g & 63;
                    ((short*)Out)[(((size_t)(b * NHEAD + h)) * S_LEN + s) * DHEAD + d] = f2bf(val);
                } else if constexpr (OMODE == 1) {
                    int b = m_g >> 11, s = m_g & 2047, h = n_g >> 6, d = n_g & 63;
                    ((short*)Out)[(((size_t)(b * NHEAD + h)) * DHEAD + d) * S_LEN + s] = f2bf(val);
                } else {
                    ((float*)Out)[(size_t)m_g * HIDN + n_g] = val;
                }
            }
        }
    }
}

// ---------------- flash attention (causal), swapped-QK^T 32x32 structure ----------------
// grid = 64 (b,h) * 16 q-tiles (128 q-rows each). block = 256 (4 waves, 32 q-rows/wave).
// Qh,Kh: [B,H,S,D] bf16 (Q pre-scaled by 0.125*log2e).  VhT: [B,H,D,S] bf16.
// ctx out: [B,S,H*D] bf16.
__global__ __launch_bounds__(256) void attn_kernel(const short* __restrict__ Qh,
                                                   const short* __restrict__ Kh,
                                                   const short* __restrict__ VhT,
                                                   short* __restrict__ ctx) {
    int bid = blockIdx.x;
    int bh = bid >> 4;
    int jj = bid & 15;
    int qt = (jj & 1) ? (jj >> 1) : (15 - (jj >> 1));  // pair heavy+light
    int tid = threadIdx.x;
    int w = tid >> 6, l = tid & 63;
    int ql = l & 31, hi = l >> 5;

    __shared__ short KV[2][2][64 * 64];  // [buf][K/V][row*64 + swizzled col] = 32 KB

    const short* Qb = Qh + (size_t)bh * (S_LEN * DHEAD);
    const short* Kb = Kh + (size_t)bh * (S_LEN * DHEAD);
    const short* Vb = VhT + (size_t)bh * (DHEAD * S_LEN);

    int q_g = qt * 128 + w * 32 + ql;
    // Q as B-operand fragments: lane holds col q=ql, d = dk*16 + hi*8 + j
    const short* qp = Qb + (size_t)q_g * DHEAD + hi * 8;
    short8 qf0 = *(const short8*)(qp);
    short8 qf1 = *(const short8*)(qp + 16);
    short8 qf2 = *(const short8*)(qp + 32);
    short8 qf3 = *(const short8*)(qp + 48);

    f32x16 accA, accB;  // ctx^T: lane holds q=ql, d = dn*32 + (reg&3)+8*(reg>>2)+4*hi
#pragma unroll
    for (int i = 0; i < 16; ++i) { accA[i] = 0.f; accB[i] = 0.f; }
    float mrun = -1e30f, lrun = 0.f;

    int ktp = (qt * 128 + w * 32) >> 6;  // this wave's single partial (diagonal) tile
    int nt = 2 * qt + 2;

    // staging coords: 2 chunks of 16B per thread per 8KB tile
    int srow0 = tid >> 3, srow1 = srow0 + 32;
    int scol = (tid & 7) * 8;  // shorts
    int wo0 = srow0 * 64 + (scol ^ ((srow0 & 7) << 3));
    int wo1 = srow1 * 64 + (scol ^ ((srow1 & 7) << 3));

    {  // prologue: stage tile 0
        short8 k0 = *(const short8*)(Kb + srow0 * 64 + scol);
        short8 k1 = *(const short8*)(Kb + srow1 * 64 + scol);
        short8 v0 = *(const short8*)(Vb + (size_t)srow0 * S_LEN + scol);
        short8 v1 = *(const short8*)(Vb + (size_t)srow1 * S_LEN + scol);
        *(short8*)(&KV[0][0][wo0]) = k0;
        *(short8*)(&KV[0][0][wo1]) = k1;
        *(short8*)(&KV[0][1][wo0]) = v0;
        *(short8*)(&KV[0][1][wo1]) = v1;
    }

    int r0 = ql, r1 = 32 + ql;
    int sw = (ql & 7) << 3;  // swizzle in shorts (16B granules)
    int ch = hi * 8;

    for (int kt = 0; kt < nt; ++kt) {
        __syncthreads();
        int cur = kt & 1;
        short8 pk0, pk1, pv0, pv1;
        bool pf = (kt + 1 < nt);
        if (pf) {  // issue next-tile loads early; HBM latency hides under compute
            const short* Kt = Kb + (kt + 1) * (64 * DHEAD);
            const short* Vt = Vb + (kt + 1) * 64;
            pk0 = *(const short8*)(Kt + srow0 * 64 + scol);
            pk1 = *(const short8*)(Kt + srow1 * 64 + scol);
            pv0 = *(const short8*)(Vt + (size_t)srow0 * S_LEN + scol);
            pv1 = *(const short8*)(Vt + (size_t)srow1 * S_LEN + scol);
        }
        if (kt <= ktp) {
            const short* Ksb = &KV[cur][0][0];
            const short* Vsb = &KV[cur][1][0];
            // S^T = K Q^T : lane -> q=ql, k = kt2*32 + (reg&3)+8*(reg>>2)+4*hi
            f32x16 st0, st1;
#pragma unroll
            for (int i = 0; i < 16; ++i) { st0[i] = 0.f; st1[i] = 0.f; }
            {
                short8 kA, kB;
                kA = *(const short8*)(Ksb + r0 * 64 + ((0 + ch) ^ sw));
                kB = *(const short8*)(Ksb + r1 * 64 + ((0 + ch) ^ sw));
                st0 = __builtin_amdgcn_mfma_f32_32x32x16_bf16(kA, qf0, st0, 0, 0, 0);
                st1 = __builtin_amdgcn_mfma_f32_32x32x16_bf16(kB, qf0, st1, 0, 0, 0);
                kA = *(const short8*)(Ksb + r0 * 64 + ((16 + ch) ^ sw));
                kB = *(const short8*)(Ksb + r1 * 64 + ((16 + ch) ^ sw));
                st0 = __builtin_amdgcn_mfma_f32_32x32x16_bf16(kA, qf1, st0, 0, 0, 0);
                st1 = __builtin_amdgcn_mfma_f32_32x32x16_bf16(kB, qf1, st1, 0, 0, 0);
                kA = *(const short8*)(Ksb + r0 * 64 + ((32 + ch) ^ sw));
                kB = *(const short8*)(Ksb + r1 * 64 + ((32 + ch) ^ sw));
                st0 = __builtin_amdgcn_mfma_f32_32x32x16_bf16(kA, qf2, st0, 0, 0, 0);
                st1 = __builtin_amdgcn_mfma_f32_32x32x16_bf16(kB, qf2, st1, 0, 0, 0);
                kA = *(const short8*)(Ksb + r0 * 64 + ((48 + ch) ^ sw));
                kB = *(const short8*)(Ksb + r1 * 64 + ((48 + ch) ^ sw));
                st0 = __builtin_amdgcn_mfma_f32_32x32x16_bf16(kA, qf3, st0, 0, 0, 0);
                st1 = __builtin_amdgcn_mfma_f32_32x32x16_bf16(kB, qf3, st1, 0, 0, 0);
            }
            float p[32];
#pragma unroll
            for (int i = 0; i < 16; ++i) { p[i] = st0[i]; p[16 + i] = st1[i]; }
            if (kt == ktp) {  // diagonal tile: per-element causal mask
#pragma unroll
                for (int i = 0; i < 32; ++i) {
                    int kl = (i & 3) + 8 * ((i >> 2) & 3) + 32 * (i >> 4) + 4 * hi;
                    if (kt * 64 + kl > q_g) p[i] = -1e30f;
                }
            }
            // row max: in-register tree + cross-half shfl (lane^32) combine
            float t[16];
#pragma unroll
            for (int i = 0; i < 16; ++i) t[i] = fmaxf(p[i], p[i + 16]);
#pragma unroll
            for (int i = 0; i < 8; ++i) t[i] = fmaxf(t[i], t[i + 8]);
#pragma unroll
            for (int i = 0; i < 4; ++i) t[i] = fmaxf(t[i], t[i + 4]);
            float pm = fmaxf(fmaxf(t[0], t[1]), fmaxf(t[2], t[3]));
            pm = fmaxf(pm, __shfl_xor(pm, 32));
            float mn = fmaxf(mrun, pm);
            float fac = exp2f(mrun - mn);  // exp2-domain (log2e folded into Q scale)
            mrun = mn;
#pragma unroll
            for (int i = 0; i < 32; ++i) p[i] = exp2f(p[i] - mn);
#pragma unroll
            for (int i = 0; i < 16; ++i) t[i] = p[i] + p[i + 16];
#pragma unroll
            for (int i = 0; i < 8; ++i) t[i] = t[i] + t[i + 8];
#pragma unroll
            for (int i = 0; i < 4; ++i) t[i] = t[i] + t[i + 4];
            float rs = (t[0] + t[1]) + (t[2] + t[3]);
            rs += __shfl_xor(rs, 32);
            lrun = lrun * fac + rs;
            accA *= fac;
            accB *= fac;
            // pack P -> bf16 B-operand frags (cvt_pk + permlane32_swap), then PV
            {
                unsigned u0 = cvtpk(p[0], p[1]);
                unsigned u1 = cvtpk(p[2], p[3]);
                unsigned u2 = cvtpk(p[4], p[5]);
                unsigned u3 = cvtpk(p[6], p[7]);
                plswap(u0, u2);
                plswap(u1, u3);
                short8 pfA = mk8(u0, u1, u2, u3);
                unsigned u4 = cvtpk(p[8], p[9]);
                unsigned u5 = cvtpk(p[10], p[11]);
                unsigned u6 = cvtpk(p[12], p[13]);
                unsigned u7 = cvtpk(p[14], p[15]);
                plswap(u4, u6);
                plswap(u5, u7);
                short8 pfB = mk8(u4, u5, u6, u7);
                short8 vA0 = *(const short8*)(Vsb + r0 * 64 + ((0 + ch) ^ sw));
                short8 vB0 = *(const short8*)(Vsb + r1 * 64 + ((0 + ch) ^ sw));
                short8 vA1 = *(const short8*)(Vsb + r0 * 64 + ((16 + ch) ^ sw));
                short8 vB1 = *(const short8*)(Vsb + r1 * 64 + ((16 + ch) ^ sw));
                accA = __builtin_amdgcn_mfma_f32_32x32x16_bf16(vA0, pfA, accA, 0, 0, 0);
                accB = __builtin_amdgcn_mfma_f32_32x32x16_bf16(vB0, pfA, accB, 0, 0, 0);
                accA = __builtin_amdgcn_mfma_f32_32x32x16_bf16(vA1, pfB, accA, 0, 0, 0);
                accB = __builtin_amdgcn_mfma_f32_32x32x16_bf16(vB1, pfB, accB, 0, 0, 0);
            }
            {
                unsigned u0 = cvtpk(p[16], p[17]);
                unsigned u1 = cvtpk(p[18], p[19]);
                unsigned u2 = cvtpk(p[20], p[21]);
                unsigned u3 = cvtpk(p[22], p[23]);
                plswap(u0, u2);
                plswap(u1, u3);
                short8 pfC = mk8(u0, u1, u2, u3);
                unsigned u4 = cvtpk(p[24], p[25]);
                unsigned u5 = cvtpk(p[26], p[27]);
                unsigned u6 = cvtpk(p[28], p[29]);
                unsigned u7 = cvtpk(p[30], p[31]);
                plswap(u4, u6);
                plswap(u5, u7);
                short8 pfD = mk8(u4, u5, u6, u7);
                short8 vA2 = *(const short8*)(Vsb + r0 * 64 + ((32 + ch) ^ sw));
                short8 vB2 = *(const short8*)(Vsb + r1 * 64 + ((32 + ch) ^ sw));
                short8 vA3 = *(const short8*)(Vsb + r0 * 64 + ((48 + ch) ^ sw));
                short8 vB3 = *(const short8*)(Vsb + r1 * 64 + ((48 + ch) ^ sw));
                accA = __builtin_amdgcn_mfma_f32_32x32x16_bf16(vA2, pfC, accA, 0, 0, 0);
                accB = __builtin_amdgcn_mfma_f32_32x32x16_bf16(vB2, pfC, accB, 0, 0, 0);
                accA = __builtin_amdgcn_mfma_f32_32x32x16_bf16(vA3, pfD, accA, 0, 0, 0);
                accB = __builtin_amdgcn_mfma_f32_32x32x16_bf16(vB3, pfD, accB, 0, 0, 0);
            }
        }
        if (pf) {  // write next tile into the other buffer (safe: all waves past barrier)
            int nb = (kt + 1) & 1;
            *(short8*)(&KV[nb][0][wo0]) = pk0;
            *(short8*)(&KV[nb][0][wo1]) = pk1;
            *(short8*)(&KV[nb][1][wo0]) = pv0;
            *(short8*)(&KV[nb][1][wo1]) = pv1;
        }
    }

    float inv = 1.0f / lrun;
    int b = bh >> 4, h = bh & 15;
    short* cb = ctx + ((size_t)(b * S_LEN + q_g)) * HIDN + h * DHEAD;
#pragma unroll
    for (int i = 0; i < 16; ++i) {
        int d0 = (i & 3) + 8 * (i >> 2) + 4 * hi;
        cb[d0] = f2bf(accA[i] * inv);
        cb[32 + d0] = f2bf(accB[i] * inv);
    }
}

extern "C" void kernel_launch(void* const* d_in, const int* in_sizes, int n_in,
                              void* d_out, int out_size, void* d_ws, size_t ws_size,
                              hipStream_t stream) {
    const float* q  = (const float*)d_in[0];
    const float* k  = (const float*)d_in[1];
    const float* v  = (const float*)d_in[2];
    // d_in[3] = attn_mask: structurally causal, not read.
    const float* Wq = (const float*)d_in[4];
    const float* bq = (const float*)d_in[5];
    const float* Wk = (const float*)d_in[6];
    const float* bk = (const float*)d_in[7];
    const float* Wv = (const float*)d_in[8];
    const float* bv = (const float*)d_in[9];
    const float* Wo = (const float*)d_in[10];
    const float* bo = (const float*)d_in[11];

    char* ws = (char*)d_ws;
    const size_t ACT = (size_t)8192 * 1024 * 2;
    const size_t WSZ = (size_t)1024 * 1024 * 2;
    short* Qh  = (short*)(ws);
    short* Kh  = (short*)(ws + ACT);
    short* VhT = (short*)(ws + 2 * ACT);
    short* ctx = (short*)(ws + 3 * ACT);
    short* Wqb = (short*)(ws + 4 * ACT);
    short* Wkb = (short*)(ws + 4 * ACT + WSZ);
    short* Wvb = (short*)(ws + 4 * ACT + 2 * WSZ);
    short* Wob = (short*)(ws + 4 * ACT + 3 * WSZ);

    const int NW = 1024 * 1024;
    cvt_kernel<<<512, 256, 0, stream>>>(Wq, Wqb, NW);
    cvt_kernel<<<512, 256, 0, stream>>>(Wk, Wkb, NW);
    cvt_kernel<<<512, 256, 0, stream>>>(Wv, Wvb, NW);
    cvt_kernel<<<512, 256, 0, stream>>>(Wo, Wob, NW);

    // Q pre-scaled by (1/sqrt(D)) * log2(e) so attention runs in exp2 domain.
    const float QSCALE = 0.125f * 1.44269504088896340736f;
    gemm_bt<true, 0><<<512, 256, 0, stream>>>(q, Wqb, bq, Qh, QSCALE);
    gemm_bt<true, 0><<<512, 256, 0, stream>>>(k, Wkb, bk, Kh, 1.0f);
    gemm_bt<true, 1><<<512, 256, 0, stream>>>(v, Wvb, bv, VhT, 1.0f);

    attn_kernel<<<1024, 256, 0, stream>>>(Qh, Kh, VhT, ctx);

    gemm_bt<false, 2><<<512, 256, 0, stream>>>(ctx, Wob, bo, d_out, 1.0f);
}

// Round 4
// 306.659 us; speedup vs baseline: 1.2488x; 1.0151x over previous
//
#include <hip/hip_runtime.h>

typedef __attribute__((ext_vector_type(8))) short short8;
typedef __attribute__((ext_vector_type(4))) float f32x4;
typedef __attribute__((ext_vector_type(16))) float f32x16;

#define S_LEN 2048
#define HIDN  1024
#define NHEAD 16
#define DHEAD 64

__device__ __forceinline__ short f2bf(float x) {
    unsigned u = __float_as_uint(x);
    u += 0x7fffu + ((u >> 16) & 1u);
    return (short)(u >> 16);
}

typedef const __attribute__((address_space(1))) void* gas_ptr;
typedef __attribute__((address_space(3))) void* las_ptr;

__device__ __forceinline__ void gload_lds16(const short* g, short* l) {
    __builtin_amdgcn_global_load_lds((gas_ptr)g, (las_ptr)l, 16, 0, 0);
}

__device__ __forceinline__ unsigned cvtpk(float lo, float hi_) {
    unsigned r;
    asm("v_cvt_pk_bf16_f32 %0, %1, %2" : "=v"(r) : "v"(lo), "v"(hi_));
    return r;
}

// v_permlane32_swap_b32 vdst, vsrc: vdst upper-half lanes <-> vsrc lower-half lanes.
__device__ __forceinline__ void plswap(unsigned& x, unsigned& y) {
    asm("v_permlane32_swap_b32 %0, %1" : "+&v"(x), "+&v"(y));
}

__device__ __forceinline__ short8 mk8(unsigned a, unsigned b, unsigned c, unsigned d) {
    union { unsigned u[4]; short8 s; } t;
    t.u[0] = a; t.u[1] = b; t.u[2] = c; t.u[3] = d;
    return t.s;
}

// ---------------- fp32 -> bf16 conversion, 4 weight matrices in one launch ----------------
__global__ __launch_bounds__(256) void cvt4_kernel(const float* __restrict__ w0,
                                                   const float* __restrict__ w1,
                                                   const float* __restrict__ w2,
                                                   const float* __restrict__ w3,
                                                   short* __restrict__ o0,
                                                   short* __restrict__ o1,
                                                   short* __restrict__ o2,
                                                   short* __restrict__ o3) {
    int which = blockIdx.x >> 9;
    const float* in = which == 0 ? w0 : which == 1 ? w1 : which == 2 ? w2 : w3;
    short* out = which == 0 ? o0 : which == 1 ? o1 : which == 2 ? o2 : o3;
    int i = ((blockIdx.x & 511) * 256 + threadIdx.x) * 8;
    float4 a = *(const float4*)(in + i);
    float4 b = *(const float4*)(in + i + 4);
    short8 o;
    o[0] = f2bf(a.x); o[1] = f2bf(a.y); o[2] = f2bf(a.z); o[3] = f2bf(a.w);
    o[4] = f2bf(b.x); o[5] = f2bf(b.y); o[6] = f2bf(b.z); o[7] = f2bf(b.w);
    *(short8*)(out + i) = o;
}

// ---------------- GEMM: C[M,N] = (A[M,K] @ W[N,K]^T + bias) * oscale ----------------
template<bool A_FP32, int OMODE>
__global__ __launch_bounds__(256) void gemm_bt(const void* __restrict__ Aptr,
                                               const short* __restrict__ Wb,
                                               const float* __restrict__ bias,
                                               void* __restrict__ Out, float oscale) {
    int mt = blockIdx.x & 63;
    int nt = blockIdx.x >> 6;
    int m0 = mt * 128, n0 = nt * 128;
    int tid = threadIdx.x;
    int w = tid >> 6, l = tid & 63, g = l >> 4, r = l & 15;
    int wm = w >> 1, wn = w & 1;

    __shared__ short As[128 * 32];
    __shared__ short Bs[128 * 32];

    f32x4 acc[4][4];
#pragma unroll
    for (int i = 0; i < 4; i++)
#pragma unroll
        for (int j = 0; j < 4; j++) acc[i][j] = (f32x4){0.f, 0.f, 0.f, 0.f};

    for (int kt = 0; kt < HIDN / 32; ++kt) {
        __syncthreads();
        if constexpr (A_FP32) {
            const float* A = (const float*)Aptr;
            int row = tid >> 1, colh = (tid & 1) * 16;
            const float* gp = A + (size_t)(m0 + row) * HIDN + kt * 32 + colh;
            float4 v0 = ((const float4*)gp)[0];
            float4 v1 = ((const float4*)gp)[1];
            float4 v2 = ((const float4*)gp)[2];
            float4 v3 = ((const float4*)gp)[3];
            short8 p0, p1;
            p0[0] = f2bf(v0.x); p0[1] = f2bf(v0.y); p0[2] = f2bf(v0.z); p0[3] = f2bf(v0.w);
            p0[4] = f2bf(v1.x); p0[5] = f2bf(v1.y); p0[6] = f2bf(v1.z); p0[7] = f2bf(v1.w);
            p1[0] = f2bf(v2.x); p1[1] = f2bf(v2.y); p1[2] = f2bf(v2.z); p1[3] = f2bf(v2.w);
            p1[4] = f2bf(v3.x); p1[5] = f2bf(v3.y); p1[6] = f2bf(v3.z); p1[7] = f2bf(v3.w);
            *(short8*)(As + row * 32 + colh) = p0;
            *(short8*)(As + row * 32 + colh + 8) = p1;
        } else {
            const short* A = (const short*)Aptr;
#pragma unroll
            for (int i = 0; i < 2; i++) {
                int c = w + i * 4;
                int o = c * 1024 + l * 16;
                int row = o >> 6, colB = o & 63;
                gload_lds16(A + (size_t)(m0 + row) * HIDN + kt * 32 + (colB >> 1),
                            As + c * 512);
            }
        }
#pragma unroll
        for (int i = 0; i < 2; i++) {
            int c = w + i * 4;
            int o = c * 1024 + l * 16;
            int row = o >> 6, colB = o & 63;
            gload_lds16(Wb + (size_t)(n0 + row) * HIDN + kt * 32 + (colB >> 1),
                        Bs + c * 512);
        }
        __syncthreads();

        short8 af[4], bfr[4];
#pragma unroll
        for (int i = 0; i < 4; i++)
            af[i] = *(const short8*)(As + (wm * 64 + i * 16 + r) * 32 + g * 8);
#pragma unroll
        for (int j = 0; j < 4; j++)
            bfr[j] = *(const short8*)(Bs + (wn * 64 + j * 16 + r) * 32 + g * 8);
#pragma unroll
        for (int i = 0; i < 4; i++)
#pragma unroll
            for (int j = 0; j < 4; j++)
                acc[i][j] = __builtin_amdgcn_mfma_f32_16x16x32_bf16(af[i], bfr[j], acc[i][j], 0, 0, 0);
    }

#pragma unroll
    for (int j = 0; j < 4; j++) {
        int n_g = n0 + wn * 64 + j * 16 + r;
        float bv = bias[n_g];
#pragma unroll
        for (int i = 0; i < 4; i++) {
#pragma unroll
            for (int rr = 0; rr < 4; rr++) {
                int m_g = m0 + wm * 64 + i * 16 + g * 4 + rr;
                float val = (acc[i][j][rr] + bv) * oscale;
                if constexpr (OMODE == 0) {
                    int b = m_g >> 11, s = m_g & 2047, h = n_g >> 6, d = n_g & 63;
                    ((short*)Out)[(((size_t)(b * NHEAD + h)) * S_LEN + s) * DHEAD + d] = f2bf(val);
                } else if constexpr (OMODE == 1) {
                    int b = m_g >> 11, s = m_g & 2047, h = n_g >> 6, d = n_g & 63;
                    ((short*)Out)[(((size_t)(b * NHEAD + h)) * DHEAD + d) * S_LEN + s] = f2bf(val);
                } else {
                    ((float*)Out)[(size_t)m_g * HIDN + n_g] = val;
                }
            }
        }
    }
}

// ---------------- flash attention (causal), swapped-QK^T 32x32 structure ----------------
// grid = 64 (b,h) * 16 q-tiles (128 q-rows each). block = 256 (4 waves, 32 q-rows/wave).
// qt mapping chosen so XCD residue class r gets {r, 15-r}: per-XCD work = 17 tiles, balanced.
__global__ __launch_bounds__(256) void attn_kernel(const short* __restrict__ Qh,
                                                   const short* __restrict__ Kh,
                                                   const short* __restrict__ VhT,
                                                   short* __restrict__ ctx) {
    int bid = blockIdx.x;
    int bh = bid >> 4;
    int jj = bid & 15;
    int qt = (jj < 8) ? jj : (23 - jj);  // XCD-balanced heavy/light distribution
    int tid = threadIdx.x;
    int w = tid >> 6, l = tid & 63;
    int ql = l & 31, hi = l >> 5;

    __shared__ short KV[2][2][64 * 64];  // [buf][K/V][row*64 + swizzled col] = 32 KB

    const short* Qb = Qh + (size_t)bh * (S_LEN * DHEAD);
    const short* Kb = Kh + (size_t)bh * (S_LEN * DHEAD);
    const short* Vb = VhT + (size_t)bh * (DHEAD * S_LEN);

    int q_g = qt * 128 + w * 32 + ql;
    const short* qp = Qb + (size_t)q_g * DHEAD + hi * 8;
    short8 qf0 = *(const short8*)(qp);
    short8 qf1 = *(const short8*)(qp + 16);
    short8 qf2 = *(const short8*)(qp + 32);
    short8 qf3 = *(const short8*)(qp + 48);

    f32x16 accA, accB;  // ctx^T: lane holds q=ql, d = dn*32 + (reg&3)+8*(reg>>2)+4*hi
#pragma unroll
    for (int i = 0; i < 16; ++i) { accA[i] = 0.f; accB[i] = 0.f; }
    float mrun = -1e30f, lrun = 0.f;

    int ktp = (qt * 128 + w * 32) >> 6;  // this wave's single partial (diagonal) tile
    int nt = 2 * qt + 2;

    int srow0 = tid >> 3, srow1 = srow0 + 32;
    int scol = (tid & 7) * 8;  // shorts
    int wo0 = srow0 * 64 + (scol ^ ((srow0 & 7) << 3));
    int wo1 = srow1 * 64 + (scol ^ ((srow1 & 7) << 3));

    {  // prologue: stage tile 0
        short8 k0 = *(const short8*)(Kb + srow0 * 64 + scol);
        short8 k1 = *(const short8*)(Kb + srow1 * 64 + scol);
        short8 v0 = *(const short8*)(Vb + (size_t)srow0 * S_LEN + scol);
        short8 v1 = *(const short8*)(Vb + (size_t)srow1 * S_LEN + scol);
        *(short8*)(&KV[0][0][wo0]) = k0;
        *(short8*)(&KV[0][0][wo1]) = k1;
        *(short8*)(&KV[0][1][wo0]) = v0;
        *(short8*)(&KV[0][1][wo1]) = v1;
    }

    int r0 = ql, r1 = 32 + ql;
    int sw = (ql & 7) << 3;  // swizzle in shorts (16B granules)
    int ch = hi * 8;

    for (int kt = 0; kt < nt; ++kt) {
        __syncthreads();
        int cur = kt & 1;
        short8 pk0, pk1, pv0, pv1;
        bool pf = (kt + 1 < nt);
        if (pf) {  // issue next-tile loads early; HBM latency hides under compute
            const short* Kt = Kb + (kt + 1) * (64 * DHEAD);
            const short* Vt = Vb + (kt + 1) * 64;
            pk0 = *(const short8*)(Kt + srow0 * 64 + scol);
            pk1 = *(const short8*)(Kt + srow1 * 64 + scol);
            pv0 = *(const short8*)(Vt + (size_t)srow0 * S_LEN + scol);
            pv1 = *(const short8*)(Vt + (size_t)srow1 * S_LEN + scol);
        }
        if (kt <= ktp) {
            const short* Ksb = &KV[cur][0][0];
            const short* Vsb = &KV[cur][1][0];
            f32x16 st0, st1;
#pragma unroll
            for (int i = 0; i < 16; ++i) { st0[i] = 0.f; st1[i] = 0.f; }
            {
                short8 kA, kB;
                kA = *(const short8*)(Ksb + r0 * 64 + ((0 + ch) ^ sw));
                kB = *(const short8*)(Ksb + r1 * 64 + ((0 + ch) ^ sw));
                __builtin_amdgcn_s_setprio(1);
                st0 = __builtin_amdgcn_mfma_f32_32x32x16_bf16(kA, qf0, st0, 0, 0, 0);
                st1 = __builtin_amdgcn_mfma_f32_32x32x16_bf16(kB, qf0, st1, 0, 0, 0);
                __builtin_amdgcn_s_setprio(0);
                kA = *(const short8*)(Ksb + r0 * 64 + ((16 + ch) ^ sw));
                kB = *(const short8*)(Ksb + r1 * 64 + ((16 + ch) ^ sw));
                __builtin_amdgcn_s_setprio(1);
                st0 = __builtin_amdgcn_mfma_f32_32x32x16_bf16(kA, qf1, st0, 0, 0, 0);
                st1 = __builtin_amdgcn_mfma_f32_32x32x16_bf16(kB, qf1, st1, 0, 0, 0);
                __builtin_amdgcn_s_setprio(0);
                kA = *(const short8*)(Ksb + r0 * 64 + ((32 + ch) ^ sw));
                kB = *(const short8*)(Ksb + r1 * 64 + ((32 + ch) ^ sw));
                __builtin_amdgcn_s_setprio(1);
                st0 = __builtin_amdgcn_mfma_f32_32x32x16_bf16(kA, qf2, st0, 0, 0, 0);
                st1 = __builtin_amdgcn_mfma_f32_32x32x16_bf16(kB, qf2, st1, 0, 0, 0);
                __builtin_amdgcn_s_setprio(0);
                kA = *(const short8*)(Ksb + r0 * 64 + ((48 + ch) ^ sw));
                kB = *(const short8*)(Ksb + r1 * 64 + ((48 + ch) ^ sw));
                __builtin_amdgcn_s_setprio(1);
                st0 = __builtin_amdgcn_mfma_f32_32x32x16_bf16(kA, qf3, st0, 0, 0, 0);
                st1 = __builtin_amdgcn_mfma_f32_32x32x16_bf16(kB, qf3, st1, 0, 0, 0);
                __builtin_amdgcn_s_setprio(0);
            }
            float p[32];
#pragma unroll
            for (int i = 0; i < 16; ++i) { p[i] = st0[i]; p[16 + i] = st1[i]; }
            if (kt == ktp) {  // diagonal tile: per-element causal mask
#pragma unroll
                for (int i = 0; i < 32; ++i) {
                    int kl = (i & 3) + 8 * ((i >> 2) & 3) + 32 * (i >> 4) + 4 * hi;
                    if (kt * 64 + kl > q_g) p[i] = -1e30f;
                }
            }
            // row max: in-register tree + cross-half shfl (lane^32) combine
            float t[16];
#pragma unroll
            for (int i = 0; i < 16; ++i) t[i] = fmaxf(p[i], p[i + 16]);
#pragma unroll
            for (int i = 0; i < 8; ++i) t[i] = fmaxf(t[i], t[i + 8]);
#pragma unroll
            for (int i = 0; i < 4; ++i) t[i] = fmaxf(t[i], t[i + 4]);
            float pm = fmaxf(fmaxf(t[0], t[1]), fmaxf(t[2], t[3]));
            pm = fmaxf(pm, __shfl_xor(pm, 32));
            // exact-skip rescale: factor is exactly 1 when no row in the wave grew its max
            bool grow = !__all(pm <= mrun);
            if (grow) {
                float mn = fmaxf(mrun, pm);
                float fac = exp2f(mrun - mn);  // exp2-domain (log2e folded into Q scale)
                mrun = mn;
                lrun *= fac;
                accA *= fac;
                accB *= fac;
            }
#pragma unroll
            for (int i = 0; i < 32; ++i) p[i] = exp2f(p[i] - mrun);
#pragma unroll
            for (int i = 0; i < 16; ++i) t[i] = p[i] + p[i + 16];
#pragma unroll
            for (int i = 0; i < 8; ++i) t[i] = t[i] + t[i + 8];
#pragma unroll
            for (int i = 0; i < 4; ++i) t[i] = t[i] + t[i + 4];
            float rs = (t[0] + t[1]) + (t[2] + t[3]);
            rs += __shfl_xor(rs, 32);
            lrun += rs;
            // pack P -> bf16 B-operand frags (cvt_pk + permlane32_swap), then PV
            {
                unsigned u0 = cvtpk(p[0], p[1]);
                unsigned u1 = cvtpk(p[2], p[3]);
                unsigned u2 = cvtpk(p[4], p[5]);
                unsigned u3 = cvtpk(p[6], p[7]);
                plswap(u0, u2);
                plswap(u1, u3);
                short8 pfA = mk8(u0, u1, u2, u3);
                unsigned u4 = cvtpk(p[8], p[9]);
                unsigned u5 = cvtpk(p[10], p[11]);
                unsigned u6 = cvtpk(p[12], p[13]);
                unsigned u7 = cvtpk(p[14], p[15]);
                plswap(u4, u6);
                plswap(u5, u7);
                short8 pfB = mk8(u4, u5, u6, u7);
                short8 vA0 = *(const short8*)(Vsb + r0 * 64 + ((0 + ch) ^ sw));
                short8 vB0 = *(const short8*)(Vsb + r1 * 64 + ((0 + ch) ^ sw));
                short8 vA1 = *(const short8*)(Vsb + r0 * 64 + ((16 + ch) ^ sw));
                short8 vB1 = *(const short8*)(Vsb + r1 * 64 + ((16 + ch) ^ sw));
                __builtin_amdgcn_s_setprio(1);
                accA = __builtin_amdgcn_mfma_f32_32x32x16_bf16(vA0, pfA, accA, 0, 0, 0);
                accB = __builtin_amdgcn_mfma_f32_32x32x16_bf16(vB0, pfA, accB, 0, 0, 0);
                accA = __builtin_amdgcn_mfma_f32_32x32x16_bf16(vA1, pfB, accA, 0, 0, 0);
                accB = __builtin_amdgcn_mfma_f32_32x32x16_bf16(vB1, pfB, accB, 0, 0, 0);
                __builtin_amdgcn_s_setprio(0);
            }
            {
                unsigned u0 = cvtpk(p[16], p[17]);
                unsigned u1 = cvtpk(p[18], p[19]);
                unsigned u2 = cvtpk(p[20], p[21]);
                unsigned u3 = cvtpk(p[22], p[23]);
                plswap(u0, u2);
                plswap(u1, u3);
                short8 pfC = mk8(u0, u1, u2, u3);
                unsigned u4 = cvtpk(p[24], p[25]);
                unsigned u5 = cvtpk(p[26], p[27]);
                unsigned u6 = cvtpk(p[28], p[29]);
                unsigned u7 = cvtpk(p[30], p[31]);
                plswap(u4, u6);
                plswap(u5, u7);
                short8 pfD = mk8(u4, u5, u6, u7);
                short8 vA2 = *(const short8*)(Vsb + r0 * 64 + ((32 + ch) ^ sw));
                short8 vB2 = *(const short8*)(Vsb + r1 * 64 + ((32 + ch) ^ sw));
                short8 vA3 = *(const short8*)(Vsb + r0 * 64 + ((48 + ch) ^ sw));
                short8 vB3 = *(const short8*)(Vsb + r1 * 64 + ((48 + ch) ^ sw));
                __builtin_amdgcn_s_setprio(1);
                accA = __builtin_amdgcn_mfma_f32_32x32x16_bf16(vA2, pfC, accA, 0, 0, 0);
                accB = __builtin_amdgcn_mfma_f32_32x32x16_bf16(vB2, pfC, accB, 0, 0, 0);
                accA = __builtin_amdgcn_mfma_f32_32x32x16_bf16(vA3, pfD, accA, 0, 0, 0);
                accB = __builtin_amdgcn_mfma_f32_32x32x16_bf16(vB3, pfD, accB, 0, 0, 0);
                __builtin_amdgcn_s_setprio(0);
            }
        }
        if (pf) {  // write next tile into the other buffer (safe: all waves past barrier)
            int nb = (kt + 1) & 1;
            *(short8*)(&KV[nb][0][wo0]) = pk0;
            *(short8*)(&KV[nb][0][wo1]) = pk1;
            *(short8*)(&KV[nb][1][wo0]) = pv0;
            *(short8*)(&KV[nb][1][wo1]) = pv1;
        }
    }

    float inv = 1.0f / lrun;
    int b = bh >> 4, h = bh & 15;
    short* cb = ctx + ((size_t)(b * S_LEN + q_g)) * HIDN + h * DHEAD;
#pragma unroll
    for (int i = 0; i < 16; ++i) {
        int d0 = (i & 3) + 8 * (i >> 2) + 4 * hi;
        cb[d0] = f2bf(accA[i] * inv);
        cb[32 + d0] = f2bf(accB[i] * inv);
    }
}

extern "C" void kernel_launch(void* const* d_in, const int* in_sizes, int n_in,
                              void* d_out, int out_size, void* d_ws, size_t ws_size,
                              hipStream_t stream) {
    const float* q  = (const float*)d_in[0];
    const float* k  = (const float*)d_in[1];
    const float* v  = (const float*)d_in[2];
    // d_in[3] = attn_mask: structurally causal, not read.
    const float* Wq = (const float*)d_in[4];
    const float* bq = (const float*)d_in[5];
    const float* Wk = (const float*)d_in[6];
    const float* bk = (const float*)d_in[7];
    const float* Wv = (const float*)d_in[8];
    const float* bv = (const float*)d_in[9];
    const float* Wo = (const float*)d_in[10];
    const float* bo = (const float*)d_in[11];

    char* ws = (char*)d_ws;
    const size_t ACT = (size_t)8192 * 1024 * 2;
    const size_t WSZ = (size_t)1024 * 1024 * 2;
    short* Qh  = (short*)(ws);
    short* Kh  = (short*)(ws + ACT);
    short* VhT = (short*)(ws + 2 * ACT);
    short* ctx = (short*)(ws + 3 * ACT);
    short* Wqb = (short*)(ws + 4 * ACT);
    short* Wkb = (short*)(ws + 4 * ACT + WSZ);
    short* Wvb = (short*)(ws + 4 * ACT + 2 * WSZ);
    short* Wob = (short*)(ws + 4 * ACT + 3 * WSZ);

    cvt4_kernel<<<2048, 256, 0, stream>>>(Wq, Wk, Wv, Wo, Wqb, Wkb, Wvb, Wob);

    // Q pre-scaled by (1/sqrt(D)) * log2(e) so attention runs in exp2 domain.
    const float QSCALE = 0.125f * 1.44269504088896340736f;
    gemm_bt<true, 0><<<512, 256, 0, stream>>>(q, Wqb, bq, Qh, QSCALE);
    gemm_bt<true, 0><<<512, 256, 0, stream>>>(k, Wkb, bk, Kh, 1.0f);
    gemm_bt<true, 1><<<512, 256, 0, stream>>>(v, Wvb, bv, VhT, 1.0f);

    attn_kernel<<<1024, 256, 0, stream>>>(Qh, Kh, VhT, ctx);

    gemm_bt<false, 2><<<512, 256, 0, stream>>>(ctx, Wob, bo, d_out, 1.0f);
}

// Round 5
// 237.208 us; speedup vs baseline: 1.6144x; 1.2928x over previous
//
#include <hip/hip_runtime.h>

typedef __attribute__((ext_vector_type(8))) short short8;
typedef __attribute__((ext_vector_type(4))) float f32x4;
typedef __attribute__((ext_vector_type(16))) float f32x16;

#define S_LEN 2048
#define HIDN  1024
#define NHEAD 16
#define DHEAD 64

__device__ __forceinline__ short f2bf(float x) {
    unsigned u = __float_as_uint(x);
    u += 0x7fffu + ((u >> 16) & 1u);
    return (short)(u >> 16);
}

typedef const __attribute__((address_space(1))) void* gas_ptr;
typedef __attribute__((address_space(3))) void* las_ptr;

__device__ __forceinline__ void gload_lds16(const short* g, short* l) {
    __builtin_amdgcn_global_load_lds((gas_ptr)g, (las_ptr)l, 16, 0, 0);
}

__device__ __forceinline__ unsigned cvtpk(float lo, float hi_) {
    unsigned r;
    asm("v_cvt_pk_bf16_f32 %0, %1, %2" : "=v"(r) : "v"(lo), "v"(hi_));
    return r;
}

__device__ __forceinline__ void plswap(unsigned& x, unsigned& y) {
    asm("v_permlane32_swap_b32 %0, %1" : "+&v"(x), "+&v"(y));
}

__device__ __forceinline__ short8 mk8(unsigned a, unsigned b, unsigned c, unsigned d) {
    union { unsigned u[4]; short8 s; } t;
    t.u[0] = a; t.u[1] = b; t.u[2] = c; t.u[3] = d;
    return t.s;
}

// ---------------- fp32 -> bf16 conversion, 4 weight matrices in one launch ----------------
__global__ __launch_bounds__(256) void cvt4_kernel(const float* __restrict__ w0,
                                                   const float* __restrict__ w1,
                                                   const float* __restrict__ w2,
                                                   const float* __restrict__ w3,
                                                   short* __restrict__ o0,
                                                   short* __restrict__ o1,
                                                   short* __restrict__ o2,
                                                   short* __restrict__ o3) {
    int which = blockIdx.x >> 9;
    const float* in = which == 0 ? w0 : which == 1 ? w1 : which == 2 ? w2 : w3;
    short* out = which == 0 ? o0 : which == 1 ? o1 : which == 2 ? o2 : o3;
    int i = ((blockIdx.x & 511) * 256 + threadIdx.x) * 8;
    float4 a = *(const float4*)(in + i);
    float4 b = *(const float4*)(in + i + 4);
    short8 o;
    o[0] = f2bf(a.x); o[1] = f2bf(a.y); o[2] = f2bf(a.z); o[3] = f2bf(a.w);
    o[4] = f2bf(b.x); o[5] = f2bf(b.y); o[6] = f2bf(b.z); o[7] = f2bf(b.w);
    *(short8*)(out + i) = o;
}

// ---------------- GEMM core: C[128,128] tile of (A[M,K] @ W[N,K]^T + bias) * oscale ----------------
// A fp32 (reg-staged + converted). omode 0: bf16 head-split [B,H,S,D]; 1: bf16 [B,H,D,S].
__device__ __forceinline__ void gemm_body_f32(const float* A, const short* Wb,
                                              const float* bias, short* Out,
                                              float oscale, int omode, int bid) {
    int mt = bid & 63;
    int nt = bid >> 6;
    int m0 = mt * 128, n0 = nt * 128;
    int tid = threadIdx.x;
    int w = tid >> 6, l = tid & 63, g = l >> 4, r = l & 15;
    int wm = w >> 1, wn = w & 1;

    __shared__ short As[128 * 32];
    __shared__ short Bs[128 * 32];

    f32x4 acc[4][4];
#pragma unroll
    for (int i = 0; i < 4; i++)
#pragma unroll
        for (int j = 0; j < 4; j++) acc[i][j] = (f32x4){0.f, 0.f, 0.f, 0.f};

    for (int kt = 0; kt < HIDN / 32; ++kt) {
        __syncthreads();
        {
            int row = tid >> 1, colh = (tid & 1) * 16;
            const float* gp = A + (size_t)(m0 + row) * HIDN + kt * 32 + colh;
            float4 v0 = ((const float4*)gp)[0];
            float4 v1 = ((const float4*)gp)[1];
            float4 v2 = ((const float4*)gp)[2];
            float4 v3 = ((const float4*)gp)[3];
            short8 p0, p1;
            p0[0] = f2bf(v0.x); p0[1] = f2bf(v0.y); p0[2] = f2bf(v0.z); p0[3] = f2bf(v0.w);
            p0[4] = f2bf(v1.x); p0[5] = f2bf(v1.y); p0[6] = f2bf(v1.z); p0[7] = f2bf(v1.w);
            p1[0] = f2bf(v2.x); p1[1] = f2bf(v2.y); p1[2] = f2bf(v2.z); p1[3] = f2bf(v2.w);
            p1[4] = f2bf(v3.x); p1[5] = f2bf(v3.y); p1[6] = f2bf(v3.z); p1[7] = f2bf(v3.w);
            *(short8*)(As + row * 32 + colh) = p0;
            *(short8*)(As + row * 32 + colh + 8) = p1;
        }
#pragma unroll
        for (int i = 0; i < 2; i++) {
            int c = w + i * 4;
            int o = c * 1024 + l * 16;
            int row = o >> 6, colB = o & 63;
            gload_lds16(Wb + (size_t)(n0 + row) * HIDN + kt * 32 + (colB >> 1),
                        Bs + c * 512);
        }
        __syncthreads();

        short8 af[4], bfr[4];
#pragma unroll
        for (int i = 0; i < 4; i++)
            af[i] = *(const short8*)(As + (wm * 64 + i * 16 + r) * 32 + g * 8);
#pragma unroll
        for (int j = 0; j < 4; j++)
            bfr[j] = *(const short8*)(Bs + (wn * 64 + j * 16 + r) * 32 + g * 8);
#pragma unroll
        for (int i = 0; i < 4; i++)
#pragma unroll
            for (int j = 0; j < 4; j++)
                acc[i][j] = __builtin_amdgcn_mfma_f32_16x16x32_bf16(af[i], bfr[j], acc[i][j], 0, 0, 0);
    }

#pragma unroll
    for (int j = 0; j < 4; j++) {
        int n_g = n0 + wn * 64 + j * 16 + r;
        float bv = bias[n_g];
        int h = n_g >> 6, d = n_g & 63;
#pragma unroll
        for (int i = 0; i < 4; i++) {
#pragma unroll
            for (int rr = 0; rr < 4; rr++) {
                int m_g = m0 + wm * 64 + i * 16 + g * 4 + rr;
                float val = (acc[i][j][rr] + bv) * oscale;
                int b = m_g >> 11, s = m_g & 2047;
                size_t idx = (omode == 0)
                    ? (((size_t)(b * NHEAD + h)) * S_LEN + s) * DHEAD + d
                    : (((size_t)(b * NHEAD + h)) * DHEAD + d) * S_LEN + s;
                Out[idx] = f2bf(val);
            }
        }
    }
}

// Fused Q/K/V projections: one launch, 3*512 blocks.
__global__ __launch_bounds__(256) void gemm_qkv(const float* __restrict__ q,
                                                const float* __restrict__ k,
                                                const float* __restrict__ v,
                                                const short* __restrict__ Wqb,
                                                const short* __restrict__ Wkb,
                                                const short* __restrict__ Wvb,
                                                const float* __restrict__ bq,
                                                const float* __restrict__ bk,
                                                const float* __restrict__ bv,
                                                short* __restrict__ Qh,
                                                short* __restrict__ Kh,
                                                short* __restrict__ VhT,
                                                float qscale) {
    int which = blockIdx.x >> 9;
    int bid = blockIdx.x & 511;
    const float* A = which == 0 ? q : which == 1 ? k : v;
    const short* Wb = which == 0 ? Wqb : which == 1 ? Wkb : Wvb;
    const float* bias = which == 0 ? bq : which == 1 ? bk : bv;
    short* Out = which == 0 ? Qh : which == 1 ? Kh : VhT;
    float oscale = which == 0 ? qscale : 1.0f;
    int omode = which == 2 ? 1 : 0;
    gemm_body_f32(A, Wb, bias, Out, oscale, omode, bid);
}

// Out-projection GEMM: A bf16 (ctx), fp32 output.
__global__ __launch_bounds__(256) void gemm_out(const short* __restrict__ A,
                                                const short* __restrict__ Wb,
                                                const float* __restrict__ bias,
                                                float* __restrict__ Out) {
    int mt = blockIdx.x & 63;
    int nt = blockIdx.x >> 6;
    int m0 = mt * 128, n0 = nt * 128;
    int tid = threadIdx.x;
    int w = tid >> 6, l = tid & 63, g = l >> 4, r = l & 15;
    int wm = w >> 1, wn = w & 1;

    __shared__ short As[128 * 32];
    __shared__ short Bs[128 * 32];

    f32x4 acc[4][4];
#pragma unroll
    for (int i = 0; i < 4; i++)
#pragma unroll
        for (int j = 0; j < 4; j++) acc[i][j] = (f32x4){0.f, 0.f, 0.f, 0.f};

    for (int kt = 0; kt < HIDN / 32; ++kt) {
        __syncthreads();
#pragma unroll
        for (int i = 0; i < 2; i++) {
            int c = w + i * 4;
            int o = c * 1024 + l * 16;
            int row = o >> 6, colB = o & 63;
            gload_lds16(A + (size_t)(m0 + row) * HIDN + kt * 32 + (colB >> 1),
                        As + c * 512);
            gload_lds16(Wb + (size_t)(n0 + row) * HIDN + kt * 32 + (colB >> 1),
                        Bs + c * 512);
        }
        __syncthreads();

        short8 af[4], bfr[4];
#pragma unroll
        for (int i = 0; i < 4; i++)
            af[i] = *(const short8*)(As + (wm * 64 + i * 16 + r) * 32 + g * 8);
#pragma unroll
        for (int j = 0; j < 4; j++)
            bfr[j] = *(const short8*)(Bs + (wn * 64 + j * 16 + r) * 32 + g * 8);
#pragma unroll
        for (int i = 0; i < 4; i++)
#pragma unroll
            for (int j = 0; j < 4; j++)
                acc[i][j] = __builtin_amdgcn_mfma_f32_16x16x32_bf16(af[i], bfr[j], acc[i][j], 0, 0, 0);
    }

#pragma unroll
    for (int j = 0; j < 4; j++) {
        int n_g = n0 + wn * 64 + j * 16 + r;
        float bv = bias[n_g];
#pragma unroll
        for (int i = 0; i < 4; i++) {
#pragma unroll
            for (int rr = 0; rr < 4; rr++) {
                int m_g = m0 + wm * 64 + i * 16 + g * 4 + rr;
                Out[(size_t)m_g * HIDN + n_g] = acc[i][j][rr] + bv;
            }
        }
    }
}

// ---------------- flash attention (causal), swapped-QK^T 32x32, paired q-tiles ----------------
// grid = 64 (b,h) * 8 pairs. block = 256 (4 waves). Each block runs q-tiles {j, 15-j}
// sequentially: per-block stage-iters = (2j+2)+(2(15-j)+2) = 36, exactly uniform -> no tail.
__global__ __launch_bounds__(256) void attn_kernel(const short* __restrict__ Qh,
                                                   const short* __restrict__ Kh,
                                                   const short* __restrict__ VhT,
                                                   short* __restrict__ ctx) {
    int bid = blockIdx.x;
    int bh = bid >> 3;
    int j = bid & 7;
    int tid = threadIdx.x;
    int w = tid >> 6, l = tid & 63;
    int ql = l & 31, hi = l >> 5;

    __shared__ short KV[2][2][64 * 64];  // [buf][K/V][row*64 + swizzled col] = 32 KB

    const short* Qb = Qh + (size_t)bh * (S_LEN * DHEAD);
    const short* Kb = Kh + (size_t)bh * (S_LEN * DHEAD);
    const short* Vb = VhT + (size_t)bh * (DHEAD * S_LEN);

    int srow0 = tid >> 3, srow1 = srow0 + 32;
    int scol = (tid & 7) * 8;  // shorts
    int wo0 = srow0 * 64 + (scol ^ ((srow0 & 7) << 3));
    int wo1 = srow1 * 64 + (scol ^ ((srow1 & 7) << 3));

    int r0 = ql, r1 = 32 + ql;
    int sw = (ql & 7) << 3;
    int ch = hi * 8;

    int b = bh >> 4, h = bh & 15;

    for (int half = 0; half < 2; ++half) {
        int qt = half ? (15 - j) : j;
        int q_g = qt * 128 + w * 32 + ql;
        const short* qp = Qb + (size_t)q_g * DHEAD + hi * 8;
        short8 qf0 = *(const short8*)(qp);
        short8 qf1 = *(const short8*)(qp + 16);
        short8 qf2 = *(const short8*)(qp + 32);
        short8 qf3 = *(const short8*)(qp + 48);

        f32x16 accA, accB;  // ctx^T: lane holds q=ql, d = dn*32 + (reg&3)+8*(reg>>2)+4*hi
#pragma unroll
        for (int i = 0; i < 16; ++i) { accA[i] = 0.f; accB[i] = 0.f; }
        float mrun = -1e30f, lrun = 0.f;

        int ktp = (qt * 128 + w * 32) >> 6;  // this wave's diagonal tile
        int nt = 2 * qt + 2;

        __syncthreads();  // guard KV reuse across halves
        {  // prologue: stage tile 0 into buf 0
            short8 k0 = *(const short8*)(Kb + srow0 * 64 + scol);
            short8 k1 = *(const short8*)(Kb + srow1 * 64 + scol);
            short8 v0 = *(const short8*)(Vb + (size_t)srow0 * S_LEN + scol);
            short8 v1 = *(const short8*)(Vb + (size_t)srow1 * S_LEN + scol);
            *(short8*)(&KV[0][0][wo0]) = k0;
            *(short8*)(&KV[0][0][wo1]) = k1;
            *(short8*)(&KV[0][1][wo0]) = v0;
            *(short8*)(&KV[0][1][wo1]) = v1;
        }

        for (int kt = 0; kt < nt; ++kt) {
            __syncthreads();
            int cur = kt & 1;
            short8 pk0, pk1, pv0, pv1;
            bool pf = (kt + 1 < nt);
            if (pf) {  // issue next-tile loads early; HBM latency hides under compute
                const short* Kt = Kb + (kt + 1) * (64 * DHEAD);
                const short* Vt = Vb + (kt + 1) * 64;
                pk0 = *(const short8*)(Kt + srow0 * 64 + scol);
                pk1 = *(const short8*)(Kt + srow1 * 64 + scol);
                pv0 = *(const short8*)(Vt + (size_t)srow0 * S_LEN + scol);
                pv1 = *(const short8*)(Vt + (size_t)srow1 * S_LEN + scol);
            }
            if (kt <= ktp) {
                const short* Ksb = &KV[cur][0][0];
                const short* Vsb = &KV[cur][1][0];
                f32x16 st0, st1;
#pragma unroll
                for (int i = 0; i < 16; ++i) { st0[i] = 0.f; st1[i] = 0.f; }
                {
                    short8 kA, kB;
                    kA = *(const short8*)(Ksb + r0 * 64 + ((0 + ch) ^ sw));
                    kB = *(const short8*)(Ksb + r1 * 64 + ((0 + ch) ^ sw));
                    __builtin_amdgcn_s_setprio(1);
                    st0 = __builtin_amdgcn_mfma_f32_32x32x16_bf16(kA, qf0, st0, 0, 0, 0);
                    st1 = __builtin_amdgcn_mfma_f32_32x32x16_bf16(kB, qf0, st1, 0, 0, 0);
                    __builtin_amdgcn_s_setprio(0);
                    kA = *(const short8*)(Ksb + r0 * 64 + ((16 + ch) ^ sw));
                    kB = *(const short8*)(Ksb + r1 * 64 + ((16 + ch) ^ sw));
                    __builtin_amdgcn_s_setprio(1);
                    st0 = __builtin_amdgcn_mfma_f32_32x32x16_bf16(kA, qf1, st0, 0, 0, 0);
                    st1 = __builtin_amdgcn_mfma_f32_32x32x16_bf16(kB, qf1, st1, 0, 0, 0);
                    __builtin_amdgcn_s_setprio(0);
                    kA = *(const short8*)(Ksb + r0 * 64 + ((32 + ch) ^ sw));
                    kB = *(const short8*)(Ksb + r1 * 64 + ((32 + ch) ^ sw));
                    __builtin_amdgcn_s_setprio(1);
                    st0 = __builtin_amdgcn_mfma_f32_32x32x16_bf16(kA, qf2, st0, 0, 0, 0);
                    st1 = __builtin_amdgcn_mfma_f32_32x32x16_bf16(kB, qf2, st1, 0, 0, 0);
                    __builtin_amdgcn_s_setprio(0);
                    kA = *(const short8*)(Ksb + r0 * 64 + ((48 + ch) ^ sw));
                    kB = *(const short8*)(Ksb + r1 * 64 + ((48 + ch) ^ sw));
                    __builtin_amdgcn_s_setprio(1);
                    st0 = __builtin_amdgcn_mfma_f32_32x32x16_bf16(kA, qf3, st0, 0, 0, 0);
                    st1 = __builtin_amdgcn_mfma_f32_32x32x16_bf16(kB, qf3, st1, 0, 0, 0);
                    __builtin_amdgcn_s_setprio(0);
                }
                float p[32];
#pragma unroll
                for (int i = 0; i < 16; ++i) { p[i] = st0[i]; p[16 + i] = st1[i]; }
                if (kt == ktp) {  // diagonal tile: per-element causal mask
#pragma unroll
                    for (int i = 0; i < 32; ++i) {
                        int kl = (i & 3) + 8 * ((i >> 2) & 3) + 32 * (i >> 4) + 4 * hi;
                        if (kt * 64 + kl > q_g) p[i] = -1e30f;
                    }
                }
                float t[16];
#pragma unroll
                for (int i = 0; i < 16; ++i) t[i] = fmaxf(p[i], p[i + 16]);
#pragma unroll
                for (int i = 0; i < 8; ++i) t[i] = fmaxf(t[i], t[i + 8]);
#pragma unroll
                for (int i = 0; i < 4; ++i) t[i] = fmaxf(t[i], t[i + 4]);
                float pm = fmaxf(fmaxf(t[0], t[1]), fmaxf(t[2], t[3]));
                pm = fmaxf(pm, __shfl_xor(pm, 32));
                bool grow = !__all(pm <= mrun);
                if (grow) {
                    float mn = fmaxf(mrun, pm);
                    float fac = exp2f(mrun - mn);
                    mrun = mn;
                    lrun *= fac;
                    accA *= fac;
                    accB *= fac;
                }
#pragma unroll
                for (int i = 0; i < 32; ++i) p[i] = exp2f(p[i] - mrun);
#pragma unroll
                for (int i = 0; i < 16; ++i) t[i] = p[i] + p[i + 16];
#pragma unroll
                for (int i = 0; i < 8; ++i) t[i] = t[i] + t[i + 8];
#pragma unroll
                for (int i = 0; i < 4; ++i) t[i] = t[i] + t[i + 4];
                float rs = (t[0] + t[1]) + (t[2] + t[3]);
                rs += __shfl_xor(rs, 32);
                lrun += rs;
                {
                    unsigned u0 = cvtpk(p[0], p[1]);
                    unsigned u1 = cvtpk(p[2], p[3]);
                    unsigned u2 = cvtpk(p[4], p[5]);
                    unsigned u3 = cvtpk(p[6], p[7]);
                    plswap(u0, u2);
                    plswap(u1, u3);
                    short8 pfA = mk8(u0, u1, u2, u3);
                    unsigned u4 = cvtpk(p[8], p[9]);
                    unsigned u5 = cvtpk(p[10], p[11]);
                    unsigned u6 = cvtpk(p[12], p[13]);
                    unsigned u7 = cvtpk(p[14], p[15]);
                    plswap(u4, u6);
                    plswap(u5, u7);
                    short8 pfB = mk8(u4, u5, u6, u7);
                    short8 vA0 = *(const short8*)(Vsb + r0 * 64 + ((0 + ch) ^ sw));
                    short8 vB0 = *(const short8*)(Vsb + r1 * 64 + ((0 + ch) ^ sw));
                    short8 vA1 = *(const short8*)(Vsb + r0 * 64 + ((16 + ch) ^ sw));
                    short8 vB1 = *(const short8*)(Vsb + r1 * 64 + ((16 + ch) ^ sw));
                    __builtin_amdgcn_s_setprio(1);
                    accA = __builtin_amdgcn_mfma_f32_32x32x16_bf16(vA0, pfA, accA, 0, 0, 0);
                    accB = __builtin_amdgcn_mfma_f32_32x32x16_bf16(vB0, pfA, accB, 0, 0, 0);
                    accA = __builtin_amdgcn_mfma_f32_32x32x16_bf16(vA1, pfB, accA, 0, 0, 0);
                    accB = __builtin_amdgcn_mfma_f32_32x32x16_bf16(vB1, pfB, accB, 0, 0, 0);
                    __builtin_amdgcn_s_setprio(0);
                }
                {
                    unsigned u0 = cvtpk(p[16], p[17]);
                    unsigned u1 = cvtpk(p[18], p[19]);
                    unsigned u2 = cvtpk(p[20], p[21]);
                    unsigned u3 = cvtpk(p[22], p[23]);
                    plswap(u0, u2);
                    plswap(u1, u3);
                    short8 pfC = mk8(u0, u1, u2, u3);
                    unsigned u4 = cvtpk(p[24], p[25]);
                    unsigned u5 = cvtpk(p[26], p[27]);
                    unsigned u6 = cvtpk(p[28], p[29]);
                    unsigned u7 = cvtpk(p[30], p[31]);
                    plswap(u4, u6);
                    plswap(u5, u7);
                    short8 pfD = mk8(u4, u5, u6, u7);
                    short8 vA2 = *(const short8*)(Vsb + r0 * 64 + ((32 + ch) ^ sw));
                    short8 vB2 = *(const short8*)(Vsb + r1 * 64 + ((32 + ch) ^ sw));
                    short8 vA3 = *(const short8*)(Vsb + r0 * 64 + ((48 + ch) ^ sw));
                    short8 vB3 = *(const short8*)(Vsb + r1 * 64 + ((48 + ch) ^ sw));
                    __builtin_amdgcn_s_setprio(1);
                    accA = __builtin_amdgcn_mfma_f32_32x32x16_bf16(vA2, pfC, accA, 0, 0, 0);
                    accB = __builtin_amdgcn_mfma_f32_32x32x16_bf16(vB2, pfC, accB, 0, 0, 0);
                    accA = __builtin_amdgcn_mfma_f32_32x32x16_bf16(vA3, pfD, accA, 0, 0, 0);
                    accB = __builtin_amdgcn_mfma_f32_32x32x16_bf16(vB3, pfD, accB, 0, 0, 0);
                    __builtin_amdgcn_s_setprio(0);
                }
            }
            if (pf) {
                int nb = (kt + 1) & 1;
                *(short8*)(&KV[nb][0][wo0]) = pk0;
                *(short8*)(&KV[nb][0][wo1]) = pk1;
                *(short8*)(&KV[nb][1][wo0]) = pv0;
                *(short8*)(&KV[nb][1][wo1]) = pv1;
            }
        }

        float inv = 1.0f / lrun;
        short* cb = ctx + ((size_t)(b * S_LEN + q_g)) * HIDN + h * DHEAD;
#pragma unroll
        for (int i = 0; i < 16; ++i) {
            int d0 = (i & 3) + 8 * (i >> 2) + 4 * hi;
            cb[d0] = f2bf(accA[i] * inv);
            cb[32 + d0] = f2bf(accB[i] * inv);
        }
    }
}

extern "C" void kernel_launch(void* const* d_in, const int* in_sizes, int n_in,
                              void* d_out, int out_size, void* d_ws, size_t ws_size,
                              hipStream_t stream) {
    const float* q  = (const float*)d_in[0];
    const float* k  = (const float*)d_in[1];
    const float* v  = (const float*)d_in[2];
    // d_in[3] = attn_mask: structurally causal, not read.
    const float* Wq = (const float*)d_in[4];
    const float* bq = (const float*)d_in[5];
    const float* Wk = (const float*)d_in[6];
    const float* bk = (const float*)d_in[7];
    const float* Wv = (const float*)d_in[8];
    const float* bv = (const float*)d_in[9];
    const float* Wo = (const float*)d_in[10];
    const float* bo = (const float*)d_in[11];

    char* ws = (char*)d_ws;
    const size_t ACT = (size_t)8192 * 1024 * 2;
    const size_t WSZ = (size_t)1024 * 1024 * 2;
    short* Qh  = (short*)(ws);
    short* Kh  = (short*)(ws + ACT);
    short* VhT = (short*)(ws + 2 * ACT);
    short* ctx = (short*)(ws + 3 * ACT);
    short* Wqb = (short*)(ws + 4 * ACT);
    short* Wkb = (short*)(ws + 4 * ACT + WSZ);
    short* Wvb = (short*)(ws + 4 * ACT + 2 * WSZ);
    short* Wob = (short*)(ws + 4 * ACT + 3 * WSZ);

    cvt4_kernel<<<2048, 256, 0, stream>>>(Wq, Wk, Wv, Wo, Wqb, Wkb, Wvb, Wob);

    // Q pre-scaled by (1/sqrt(D)) * log2(e) so attention runs in exp2 domain.
    const float QSCALE = 0.125f * 1.44269504088896340736f;
    gemm_qkv<<<1536, 256, 0, stream>>>(q, k, v, Wqb, Wkb, Wvb, bq, bk, bv,
                                       Qh, Kh, VhT, QSCALE);

    attn_kernel<<<512, 256, 0, stream>>>(Qh, Kh, VhT, ctx);

    gemm_out<<<512, 256, 0, stream>>>(ctx, Wob, bo, (float*)d_out);
}

// Round 6
// 224.360 us; speedup vs baseline: 1.7069x; 1.0573x over previous
//
#include <hip/hip_runtime.h>

typedef __attribute__((ext_vector_type(8))) short short8;
typedef __attribute__((ext_vector_type(4))) float f32x4;
typedef __attribute__((ext_vector_type(16))) float f32x16;

#define S_LEN 2048
#define HIDN  1024
#define NHEAD 16
#define DHEAD 64

__device__ __forceinline__ short f2bf(float x) {
    unsigned u = __float_as_uint(x);
    u += 0x7fffu + ((u >> 16) & 1u);
    return (short)(u >> 16);
}

typedef const __attribute__((address_space(1))) void* gas_ptr;
typedef __attribute__((address_space(3))) void* las_ptr;

__device__ __forceinline__ void gload_lds16(const short* g, short* l) {
    __builtin_amdgcn_global_load_lds((gas_ptr)g, (las_ptr)l, 16, 0, 0);
}

__device__ __forceinline__ unsigned cvtpk(float lo, float hi_) {
    unsigned r;
    asm("v_cvt_pk_bf16_f32 %0, %1, %2" : "=v"(r) : "v"(lo), "v"(hi_));
    return r;
}

__device__ __forceinline__ void plswap(unsigned& x, unsigned& y) {
    asm("v_permlane32_swap_b32 %0, %1" : "+&v"(x), "+&v"(y));
}

__device__ __forceinline__ short8 mk8(unsigned a, unsigned b, unsigned c, unsigned d) {
    union { unsigned u[4]; short8 s; } t;
    t.u[0] = a; t.u[1] = b; t.u[2] = c; t.u[3] = d;
    return t.s;
}

// ---------------- fp32 -> bf16: 3 activations (4096 blocks each) + 4 weights (512 each) ----------------
__global__ __launch_bounds__(256) void cvt_all(const float* __restrict__ q,
                                               const float* __restrict__ k,
                                               const float* __restrict__ v,
                                               const float* __restrict__ Wq,
                                               const float* __restrict__ Wk,
                                               const float* __restrict__ Wv,
                                               const float* __restrict__ Wo,
                                               short* __restrict__ qb,
                                               short* __restrict__ kb,
                                               short* __restrict__ vb,
                                               short* __restrict__ wqb,
                                               short* __restrict__ wkb,
                                               short* __restrict__ wvb,
                                               short* __restrict__ wob) {
    int bid = blockIdx.x;
    const float* in;
    short* out;
    int base;
    if (bid < 4096)       { in = q; out = qb; base = bid; }
    else if (bid < 8192)  { in = k; out = kb; base = bid - 4096; }
    else if (bid < 12288) { in = v; out = vb; base = bid - 8192; }
    else {
        int t = bid - 12288;
        int wsel = t >> 9;
        base = t & 511;
        in  = wsel == 0 ? Wq  : wsel == 1 ? Wk  : wsel == 2 ? Wv  : Wo;
        out = wsel == 0 ? wqb : wsel == 1 ? wkb : wsel == 2 ? wvb : wob;
    }
    int i = (base * 256 + threadIdx.x) * 8;
    float4 a = *(const float4*)(in + i);
    float4 b = *(const float4*)(in + i + 4);
    short8 o;
    o[0] = f2bf(a.x); o[1] = f2bf(a.y); o[2] = f2bf(a.z); o[3] = f2bf(a.w);
    o[4] = f2bf(b.x); o[5] = f2bf(b.y); o[6] = f2bf(b.z); o[7] = f2bf(b.w);
    *(short8*)(out + i) = o;
}

// ---------------- GEMM core: both operands bf16, global_load_lds staging ----------------
// C[128,128] tile of (A[M,K] @ W[N,K]^T + bias) * oscale.
// omode 0: bf16 head-split [B,H,S,D]; 1: bf16 transposed [B,H,D,S].
__device__ __forceinline__ void gemm_body_bf16(const short* A, const short* Wb,
                                               const float* bias, short* Out,
                                               float oscale, int omode, int bid) {
    int mt = bid & 63;
    int nt = bid >> 6;
    int m0 = mt * 128, n0 = nt * 128;
    int tid = threadIdx.x;
    int w = tid >> 6, l = tid & 63, g = l >> 4, r = l & 15;
    int wm = w >> 1, wn = w & 1;

    __shared__ short As[128 * 32];
    __shared__ short Bs[128 * 32];

    f32x4 acc[4][4];
#pragma unroll
    for (int i = 0; i < 4; i++)
#pragma unroll
        for (int j = 0; j < 4; j++) acc[i][j] = (f32x4){0.f, 0.f, 0.f, 0.f};

    for (int kt = 0; kt < HIDN / 32; ++kt) {
        __syncthreads();
#pragma unroll
        for (int i = 0; i < 2; i++) {
            int c = w + i * 4;
            int o = c * 1024 + l * 16;
            int row = o >> 6, colB = o & 63;
            gload_lds16(A + (size_t)(m0 + row) * HIDN + kt * 32 + (colB >> 1),
                        As + c * 512);
            gload_lds16(Wb + (size_t)(n0 + row) * HIDN + kt * 32 + (colB >> 1),
                        Bs + c * 512);
        }
        __syncthreads();

        short8 af[4], bfr[4];
#pragma unroll
        for (int i = 0; i < 4; i++)
            af[i] = *(const short8*)(As + (wm * 64 + i * 16 + r) * 32 + g * 8);
#pragma unroll
        for (int j = 0; j < 4; j++)
            bfr[j] = *(const short8*)(Bs + (wn * 64 + j * 16 + r) * 32 + g * 8);
#pragma unroll
        for (int i = 0; i < 4; i++)
#pragma unroll
            for (int j = 0; j < 4; j++)
                acc[i][j] = __builtin_amdgcn_mfma_f32_16x16x32_bf16(af[i], bfr[j], acc[i][j], 0, 0, 0);
    }

#pragma unroll
    for (int j = 0; j < 4; j++) {
        int n_g = n0 + wn * 64 + j * 16 + r;
        float bv = bias[n_g];
        int h = n_g >> 6, d = n_g & 63;
#pragma unroll
        for (int i = 0; i < 4; i++) {
#pragma unroll
            for (int rr = 0; rr < 4; rr++) {
                int m_g = m0 + wm * 64 + i * 16 + g * 4 + rr;
                float val = (acc[i][j][rr] + bv) * oscale;
                int b = m_g >> 11, s = m_g & 2047;
                size_t idx = (omode == 0)
                    ? (((size_t)(b * NHEAD + h)) * S_LEN + s) * DHEAD + d
                    : (((size_t)(b * NHEAD + h)) * DHEAD + d) * S_LEN + s;
                Out[idx] = f2bf(val);
            }
        }
    }
}

// Fused Q/K/V projections (bf16 A): one launch, 3*512 blocks.
__global__ __launch_bounds__(256) void gemm_qkv(const short* __restrict__ qb,
                                                const short* __restrict__ kb,
                                                const short* __restrict__ vb,
                                                const short* __restrict__ Wqb,
                                                const short* __restrict__ Wkb,
                                                const short* __restrict__ Wvb,
                                                const float* __restrict__ bq,
                                                const float* __restrict__ bk,
                                                const float* __restrict__ bv,
                                                short* __restrict__ Qh,
                                                short* __restrict__ Kh,
                                                short* __restrict__ VhT,
                                                float qscale) {
    int which = blockIdx.x >> 9;
    int bid = blockIdx.x & 511;
    const short* A = which == 0 ? qb : which == 1 ? kb : vb;
    const short* Wb = which == 0 ? Wqb : which == 1 ? Wkb : Wvb;
    const float* bias = which == 0 ? bq : which == 1 ? bk : bv;
    short* Out = which == 0 ? Qh : which == 1 ? Kh : VhT;
    float oscale = which == 0 ? qscale : 1.0f;
    int omode = which == 2 ? 1 : 0;
    gemm_body_bf16(A, Wb, bias, Out, oscale, omode, bid);
}

// Out-projection GEMM: A bf16 (ctx), fp32 output.
__global__ __launch_bounds__(256) void gemm_out(const short* __restrict__ A,
                                                const short* __restrict__ Wb,
                                                const float* __restrict__ bias,
                                                float* __restrict__ Out) {
    int mt = blockIdx.x & 63;
    int nt = blockIdx.x >> 6;
    int m0 = mt * 128, n0 = nt * 128;
    int tid = threadIdx.x;
    int w = tid >> 6, l = tid & 63, g = l >> 4, r = l & 15;
    int wm = w >> 1, wn = w & 1;

    __shared__ short As[128 * 32];
    __shared__ short Bs[128 * 32];

    f32x4 acc[4][4];
#pragma unroll
    for (int i = 0; i < 4; i++)
#pragma unroll
        for (int j = 0; j < 4; j++) acc[i][j] = (f32x4){0.f, 0.f, 0.f, 0.f};

    for (int kt = 0; kt < HIDN / 32; ++kt) {
        __syncthreads();
#pragma unroll
        for (int i = 0; i < 2; i++) {
            int c = w + i * 4;
            int o = c * 1024 + l * 16;
            int row = o >> 6, colB = o & 63;
            gload_lds16(A + (size_t)(m0 + row) * HIDN + kt * 32 + (colB >> 1),
                        As + c * 512);
            gload_lds16(Wb + (size_t)(n0 + row) * HIDN + kt * 32 + (colB >> 1),
                        Bs + c * 512);
        }
        __syncthreads();

        short8 af[4], bfr[4];
#pragma unroll
        for (int i = 0; i < 4; i++)
            af[i] = *(const short8*)(As + (wm * 64 + i * 16 + r) * 32 + g * 8);
#pragma unroll
        for (int j = 0; j < 4; j++)
            bfr[j] = *(const short8*)(Bs + (wn * 64 + j * 16 + r) * 32 + g * 8);
#pragma unroll
        for (int i = 0; i < 4; i++)
#pragma unroll
            for (int j = 0; j < 4; j++)
                acc[i][j] = __builtin_amdgcn_mfma_f32_16x16x32_bf16(af[i], bfr[j], acc[i][j], 0, 0, 0);
    }

#pragma unroll
    for (int j = 0; j < 4; j++) {
        int n_g = n0 + wn * 64 + j * 16 + r;
        float bv = bias[n_g];
#pragma unroll
        for (int i = 0; i < 4; i++) {
#pragma unroll
            for (int rr = 0; rr < 4; rr++) {
                int m_g = m0 + wm * 64 + i * 16 + g * 4 + rr;
                Out[(size_t)m_g * HIDN + n_g] = acc[i][j][rr] + bv;
            }
        }
    }
}

// ---------------- flash attention (causal), swapped-QK^T 32x32, paired q-tiles ----------------
// grid = 64 (b,h) * 8 pairs. block = 256 (4 waves). Each block runs q-tiles {j, 15-j}
// sequentially: per-block stage-iters = (2j+2)+(2(15-j)+2) = 36, exactly uniform -> no tail.
__global__ __launch_bounds__(256) void attn_kernel(const short* __restrict__ Qh,
                                                   const short* __restrict__ Kh,
                                                   const short* __restrict__ VhT,
                                                   short* __restrict__ ctx) {
    int bid = blockIdx.x;
    int bh = bid >> 3;
    int j = bid & 7;
    int tid = threadIdx.x;
    int w = tid >> 6, l = tid & 63;
    int ql = l & 31, hi = l >> 5;

    __shared__ short KV[2][2][64 * 64];  // [buf][K/V][row*64 + swizzled col] = 32 KB

    const short* Qb = Qh + (size_t)bh * (S_LEN * DHEAD);
    const short* Kb = Kh + (size_t)bh * (S_LEN * DHEAD);
    const short* Vb = VhT + (size_t)bh * (DHEAD * S_LEN);

    int srow0 = tid >> 3, srow1 = srow0 + 32;
    int scol = (tid & 7) * 8;  // shorts
    int wo0 = srow0 * 64 + (scol ^ ((srow0 & 7) << 3));
    int wo1 = srow1 * 64 + (scol ^ ((srow1 & 7) << 3));

    int r0 = ql, r1 = 32 + ql;
    int sw = (ql & 7) << 3;
    int ch = hi * 8;

    int b = bh >> 4, h = bh & 15;

    for (int half = 0; half < 2; ++half) {
        int qt = half ? (15 - j) : j;
        int q_g = qt * 128 + w * 32 + ql;
        const short* qp = Qb + (size_t)q_g * DHEAD + hi * 8;
        short8 qf0 = *(const short8*)(qp);
        short8 qf1 = *(const short8*)(qp + 16);
        short8 qf2 = *(const short8*)(qp + 32);
        short8 qf3 = *(const short8*)(qp + 48);

        f32x16 accA, accB;  // ctx^T: lane holds q=ql, d = dn*32 + (reg&3)+8*(reg>>2)+4*hi
#pragma unroll
        for (int i = 0; i < 16; ++i) { accA[i] = 0.f; accB[i] = 0.f; }
        float mrun = -1e30f, lrun = 0.f;

        int ktp = (qt * 128 + w * 32) >> 6;  // this wave's diagonal tile
        int nt = 2 * qt + 2;

        __syncthreads();  // guard KV reuse across halves
        {  // prologue: stage tile 0 into buf 0
            short8 k0 = *(const short8*)(Kb + srow0 * 64 + scol);
            short8 k1 = *(const short8*)(Kb + srow1 * 64 + scol);
            short8 v0 = *(const short8*)(Vb + (size_t)srow0 * S_LEN + scol);
            short8 v1 = *(const short8*)(Vb + (size_t)srow1 * S_LEN + scol);
            *(short8*)(&KV[0][0][wo0]) = k0;
            *(short8*)(&KV[0][0][wo1]) = k1;
            *(short8*)(&KV[0][1][wo0]) = v0;
            *(short8*)(&KV[0][1][wo1]) = v1;
        }

        for (int kt = 0; kt < nt; ++kt) {
            __syncthreads();
            int cur = kt & 1;
            short8 pk0, pk1, pv0, pv1;
            bool pf = (kt + 1 < nt);
            if (pf) {  // issue next-tile loads early; HBM latency hides under compute
                const short* Kt = Kb + (kt + 1) * (64 * DHEAD);
                const short* Vt = Vb + (kt + 1) * 64;
                pk0 = *(const short8*)(Kt + srow0 * 64 + scol);
                pk1 = *(const short8*)(Kt + srow1 * 64 + scol);
                pv0 = *(const short8*)(Vt + (size_t)srow0 * S_LEN + scol);
                pv1 = *(const short8*)(Vt + (size_t)srow1 * S_LEN + scol);
            }
            if (kt <= ktp) {
                const short* Ksb = &KV[cur][0][0];
                const short* Vsb = &KV[cur][1][0];
                f32x16 st0, st1;
#pragma unroll
                for (int i = 0; i < 16; ++i) { st0[i] = 0.f; st1[i] = 0.f; }
                {
                    short8 kA, kB;
                    kA = *(const short8*)(Ksb + r0 * 64 + ((0 + ch) ^ sw));
                    kB = *(const short8*)(Ksb + r1 * 64 + ((0 + ch) ^ sw));
                    __builtin_amdgcn_s_setprio(1);
                    st0 = __builtin_amdgcn_mfma_f32_32x32x16_bf16(kA, qf0, st0, 0, 0, 0);
                    st1 = __builtin_amdgcn_mfma_f32_32x32x16_bf16(kB, qf0, st1, 0, 0, 0);
                    __builtin_amdgcn_s_setprio(0);
                    kA = *(const short8*)(Ksb + r0 * 64 + ((16 + ch) ^ sw));
                    kB = *(const short8*)(Ksb + r1 * 64 + ((16 + ch) ^ sw));
                    __builtin_amdgcn_s_setprio(1);
                    st0 = __builtin_amdgcn_mfma_f32_32x32x16_bf16(kA, qf1, st0, 0, 0, 0);
                    st1 = __builtin_amdgcn_mfma_f32_32x32x16_bf16(kB, qf1, st1, 0, 0, 0);
                    __builtin_amdgcn_s_setprio(0);
                    kA = *(const short8*)(Ksb + r0 * 64 + ((32 + ch) ^ sw));
                    kB = *(const short8*)(Ksb + r1 * 64 + ((32 + ch) ^ sw));
                    __builtin_amdgcn_s_setprio(1);
                    st0 = __builtin_amdgcn_mfma_f32_32x32x16_bf16(kA, qf2, st0, 0, 0, 0);
                    st1 = __builtin_amdgcn_mfma_f32_32x32x16_bf16(kB, qf2, st1, 0, 0, 0);
                    __builtin_amdgcn_s_setprio(0);
                    kA = *(const short8*)(Ksb + r0 * 64 + ((48 + ch) ^ sw));
                    kB = *(const short8*)(Ksb + r1 * 64 + ((48 + ch) ^ sw));
                    __builtin_amdgcn_s_setprio(1);
                    st0 = __builtin_amdgcn_mfma_f32_32x32x16_bf16(kA, qf3, st0, 0, 0, 0);
                    st1 = __builtin_amdgcn_mfma_f32_32x32x16_bf16(kB, qf3, st1, 0, 0, 0);
                    __builtin_amdgcn_s_setprio(0);
                }
                float p[32];
#pragma unroll
                for (int i = 0; i < 16; ++i) { p[i] = st0[i]; p[16 + i] = st1[i]; }
                if (kt == ktp) {  // diagonal tile: per-element causal mask
#pragma unroll
                    for (int i = 0; i < 32; ++i) {
                        int kl = (i & 3) + 8 * ((i >> 2) & 3) + 32 * (i >> 4) + 4 * hi;
                        if (kt * 64 + kl > q_g) p[i] = -1e30f;
                    }
                }
                float t[16];
#pragma unroll
                for (int i = 0; i < 16; ++i) t[i] = fmaxf(p[i], p[i + 16]);
#pragma unroll
                for (int i = 0; i < 8; ++i) t[i] = fmaxf(t[i], t[i + 8]);
#pragma unroll
                for (int i = 0; i < 4; ++i) t[i] = fmaxf(t[i], t[i + 4]);
                float pm = fmaxf(fmaxf(t[0], t[1]), fmaxf(t[2], t[3]));
                pm = fmaxf(pm, __shfl_xor(pm, 32));
                bool grow = !__all(pm <= mrun);
                if (grow) {
                    float mn = fmaxf(mrun, pm);
                    float fac = exp2f(mrun - mn);
                    mrun = mn;
                    lrun *= fac;
                    accA *= fac;
                    accB *= fac;
                }
#pragma unroll
                for (int i = 0; i < 32; ++i) p[i] = exp2f(p[i] - mrun);
#pragma unroll
                for (int i = 0; i < 16; ++i) t[i] = p[i] + p[i + 16];
#pragma unroll
                for (int i = 0; i < 8; ++i) t[i] = t[i] + t[i + 8];
#pragma unroll
                for (int i = 0; i < 4; ++i) t[i] = t[i] + t[i + 4];
                float rs = (t[0] + t[1]) + (t[2] + t[3]);
                rs += __shfl_xor(rs, 32);
                lrun += rs;
                {
                    unsigned u0 = cvtpk(p[0], p[1]);
                    unsigned u1 = cvtpk(p[2], p[3]);
                    unsigned u2 = cvtpk(p[4], p[5]);
                    unsigned u3 = cvtpk(p[6], p[7]);
                    plswap(u0, u2);
                    plswap(u1, u3);
                    short8 pfA = mk8(u0, u1, u2, u3);
                    unsigned u4 = cvtpk(p[8], p[9]);
                    unsigned u5 = cvtpk(p[10], p[11]);
                    unsigned u6 = cvtpk(p[12], p[13]);
                    unsigned u7 = cvtpk(p[14], p[15]);
                    plswap(u4, u6);
                    plswap(u5, u7);
                    short8 pfB = mk8(u4, u5, u6, u7);
                    short8 vA0 = *(const short8*)(Vsb + r0 * 64 + ((0 + ch) ^ sw));
                    short8 vB0 = *(const short8*)(Vsb + r1 * 64 + ((0 + ch) ^ sw));
                    short8 vA1 = *(const short8*)(Vsb + r0 * 64 + ((16 + ch) ^ sw));
                    short8 vB1 = *(const short8*)(Vsb + r1 * 64 + ((16 + ch) ^ sw));
                    __builtin_amdgcn_s_setprio(1);
                    accA = __builtin_amdgcn_mfma_f32_32x32x16_bf16(vA0, pfA, accA, 0, 0, 0);
                    accB = __builtin_amdgcn_mfma_f32_32x32x16_bf16(vB0, pfA, accB, 0, 0, 0);
                    accA = __builtin_amdgcn_mfma_f32_32x32x16_bf16(vA1, pfB, accA, 0, 0, 0);
                    accB = __builtin_amdgcn_mfma_f32_32x32x16_bf16(vB1, pfB, accB, 0, 0, 0);
                    __builtin_amdgcn_s_setprio(0);
                }
                {
                    unsigned u0 = cvtpk(p[16], p[17]);
                    unsigned u1 = cvtpk(p[18], p[19]);
                    unsigned u2 = cvtpk(p[20], p[21]);
                    unsigned u3 = cvtpk(p[22], p[23]);
                    plswap(u0, u2);
                    plswap(u1, u3);
                    short8 pfC = mk8(u0, u1, u2, u3);
                    unsigned u4 = cvtpk(p[24], p[25]);
                    unsigned u5 = cvtpk(p[26], p[27]);
                    unsigned u6 = cvtpk(p[28], p[29]);
                    unsigned u7 = cvtpk(p[30], p[31]);
                    plswap(u4, u6);
                    plswap(u5, u7);
                    short8 pfD = mk8(u4, u5, u6, u7);
                    short8 vA2 = *(const short8*)(Vsb + r0 * 64 + ((32 + ch) ^ sw));
                    short8 vB2 = *(const short8*)(Vsb + r1 * 64 + ((32 + ch) ^ sw));
                    short8 vA3 = *(const short8*)(Vsb + r0 * 64 + ((48 + ch) ^ sw));
                    short8 vB3 = *(const short8*)(Vsb + r1 * 64 + ((48 + ch) ^ sw));
                    __builtin_amdgcn_s_setprio(1);
                    accA = __builtin_amdgcn_mfma_f32_32x32x16_bf16(vA2, pfC, accA, 0, 0, 0);
                    accB = __builtin_amdgcn_mfma_f32_32x32x16_bf16(vB2, pfC, accB, 0, 0, 0);
                    accA = __builtin_amdgcn_mfma_f32_32x32x16_bf16(vA3, pfD, accA, 0, 0, 0);
                    accB = __builtin_amdgcn_mfma_f32_32x32x16_bf16(vB3, pfD, accB, 0, 0, 0);
                    __builtin_amdgcn_s_setprio(0);
                }
            }
            if (pf) {
                int nb = (kt + 1) & 1;
                *(short8*)(&KV[nb][0][wo0]) = pk0;
                *(short8*)(&KV[nb][0][wo1]) = pk1;
                *(short8*)(&KV[nb][1][wo0]) = pv0;
                *(short8*)(&KV[nb][1][wo1]) = pv1;
            }
        }

        float inv = 1.0f / lrun;
        short* cb = ctx + ((size_t)(b * S_LEN + q_g)) * HIDN + h * DHEAD;
#pragma unroll
        for (int i = 0; i < 16; ++i) {
            int d0 = (i & 3) + 8 * (i >> 2) + 4 * hi;
            cb[d0] = f2bf(accA[i] * inv);
            cb[32 + d0] = f2bf(accB[i] * inv);
        }
    }
}

extern "C" void kernel_launch(void* const* d_in, const int* in_sizes, int n_in,
                              void* d_out, int out_size, void* d_ws, size_t ws_size,
                              hipStream_t stream) {
    const float* q  = (const float*)d_in[0];
    const float* k  = (const float*)d_in[1];
    const float* v  = (const float*)d_in[2];
    // d_in[3] = attn_mask: structurally causal, not read.
    const float* Wq = (const float*)d_in[4];
    const float* bq = (const float*)d_in[5];
    const float* Wk = (const float*)d_in[6];
    const float* bk = (const float*)d_in[7];
    const float* Wv = (const float*)d_in[8];
    const float* bv = (const float*)d_in[9];
    const float* Wo = (const float*)d_in[10];
    const float* bo = (const float*)d_in[11];

    char* ws = (char*)d_ws;
    const size_t ACT = (size_t)8192 * 1024 * 2;   // 16 MB per bf16 activation
    const size_t WSZ = (size_t)1024 * 1024 * 2;   // 2 MB per bf16 weight
    short* Qh  = (short*)(ws);
    short* Kh  = (short*)(ws + ACT);
    short* VhT = (short*)(ws + 2 * ACT);
    short* qb  = (short*)(ws + 3 * ACT);          // bf16 activations for QKV GEMMs
    short* kb  = (short*)(ws + 4 * ACT);
    short* vb  = (short*)(ws + 5 * ACT);
    short* ctx = qb;                               // alias: qb dead after gemm_qkv
    short* Wqb = (short*)(ws + 6 * ACT);
    short* Wkb = (short*)(ws + 6 * ACT + WSZ);
    short* Wvb = (short*)(ws + 6 * ACT + 2 * WSZ);
    short* Wob = (short*)(ws + 6 * ACT + 3 * WSZ);
    // peak ws use: 6*16 + 8 = 104 MB

    cvt_all<<<14336, 256, 0, stream>>>(q, k, v, Wq, Wk, Wv, Wo,
                                       qb, kb, vb, Wqb, Wkb, Wvb, Wob);

    // Q pre-scaled by (1/sqrt(D)) * log2(e) so attention runs in exp2 domain.
    const float QSCALE = 0.125f * 1.44269504088896340736f;
    gemm_qkv<<<1536, 256, 0, stream>>>(qb, kb, vb, Wqb, Wkb, Wvb, bq, bk, bv,
                                       Qh, Kh, VhT, QSCALE);

    attn_kernel<<<512, 256, 0, stream>>>(Qh, Kh, VhT, ctx);

    gemm_out<<<512, 256, 0, stream>>>(ctx, Wob, bo, (float*)d_out);
}